// Round 16
// baseline (739.739 us; speedup 1.0000x reference)
//
#include <hip/hip_runtime.h>
#include <hip/hip_bf16.h>
#include <math.h>

// Problem constants
constexpr int N_   = 4096;
constexpr int E_   = 131072;
constexpr int D_   = 256;
constexpr int DIN_ = 16;
constexpr int D3_  = 768;   // 3*D
constexpr int HD_  = 128;   // head dim

typedef __bf16 bf16_8 __attribute__((ext_vector_type(8)));
typedef float  f32x4  __attribute__((ext_vector_type(4)));
typedef float  f32x4v __attribute__((ext_vector_type(4)));
typedef unsigned int u32x4 __attribute__((ext_vector_type(4)));   // NT-store-compatible 16B

// ---- bf16 helpers ----
__device__ __forceinline__ unsigned short f2b(float f) {
  unsigned int u = __float_as_uint(f);
  u = u + 0x7fffu + ((u >> 16) & 1u);   // round-to-nearest-even
  return (unsigned short)(u >> 16);
}
__device__ __forceinline__ float b2f(unsigned short s) {
  return __uint_as_float(((unsigned int)s) << 16);
}
__device__ __forceinline__ unsigned int pack2(unsigned short lo, unsigned short hi) {
  return (unsigned int)lo | ((unsigned int)hi << 16);
}
__device__ __forceinline__ bf16_8 frag16(const unsigned short* p) {
  uint4 v = *(const uint4*)p;           // 16B load (LDS b128 or global dwordx4)
  return __builtin_bit_cast(bf16_8, v);
}
__device__ __forceinline__ float4 ntload4(const void* p) {
  f32x4v v = __builtin_nontemporal_load((const f32x4v*)p);
  float4 r;
  r.x = v[0]; r.y = v[1]; r.z = v[2]; r.w = v[3];
  return r;
}
__device__ __forceinline__ void ntstore16(void* dst, uint4 v) {
  __builtin_nontemporal_store(__builtin_bit_cast(u32x4, v), (u32x4*)dst);
}
// async global->LDS, 16B per lane; LDS dst = uniform base + lane*16
__device__ __forceinline__ void gl2lds16(const unsigned short* g, unsigned short* l) {
  __builtin_amdgcn_global_load_lds(
      (const __attribute__((address_space(1))) void*)g,
      (__attribute__((address_space(3))) void*)l, 16, 0, 0);
}

// Python scalar may arrive as int32 or float32 bits; values here are small ints.
__device__ __forceinline__ float scalar_as_float(const void* p) {
  int iv = *(const int*)p;
  if (iv >= 1 && iv <= 1000000) return (float)iv;  // plausible int
  return __int_as_float(iv);                       // else float bits
}

__device__ __forceinline__ float gelu_exact(float v) {
  return 0.5f * v * (1.0f + erff(v * 0.70710678118654752f));
}

// ---------------- f32 -> bf16 convert ----------------
__global__ void k_f2b(const float* __restrict__ src, unsigned short* __restrict__ dst, int n) {
  int i = blockIdx.x * 256 + threadIdx.x;
  if (i < n) dst[i] = f2b(src[i]);
}

// ---------------- transpose + f2b: src[K,J] fp32 -> dst[J,K] bf16 ----------------
__global__ void k_tb(const float* __restrict__ src, unsigned short* __restrict__ dst,
                     int K, int J) {
  int idx = blockIdx.x * 256 + threadIdx.x;
  if (idx < K * J) {
    int k = idx % K, j = idx / K;
    dst[idx] = f2b(src[(size_t)k * J + j]);
  }
}

// ---------------- copy (float4) ----------------
__global__ void k_copy4(const float4* __restrict__ src, float4* __restrict__ dst, int n4) {
  int idx = blockIdx.x * 256 + threadIdx.x;
  if (idx < n4) dst[idx] = src[idx];
}

// ---------------- edge_attr via zero-padded MFMA ----------------
__global__ __launch_bounds__(256) void k_edge_attr_mfma(
    const float* __restrict__ dmap, const unsigned short* __restrict__ lwb,
    const float* __restrict__ lin_b, unsigned short* __restrict__ eab) {
  __shared__ unsigned short sT[4][16][264];   // per-wave C tile (bounce), 33 KB
  const int tid  = threadIdx.x;
  const int lane = tid & 63, wv = tid >> 6;
  const int r16  = lane & 15, quad = lane >> 4;
  const int e0   = blockIdx.x * 64 + wv * 16;

  const uint4 z4 = make_uint4(0u, 0u, 0u, 0u);
  bf16_8 bfr[16];
#pragma unroll
  for (int n = 0; n < 16; ++n) {
    uint4 v = z4;
    if (quad < 2) v = *(const uint4*)(lwb + (size_t)(n * 16 + r16) * DIN_ + quad * 8);
    bfr[n] = __builtin_bit_cast(bf16_8, v);
  }
  bf16_8 af;
  {
    uint4 p = z4;
    if (quad < 2) {
      const float4* dp = (const float4*)(dmap + (size_t)(e0 + r16) * DIN_ + quad * 8);
      float4 a = dp[0], b = dp[1];
      p = make_uint4(pack2(f2b(a.x), f2b(a.y)), pack2(f2b(a.z), f2b(a.w)),
                     pack2(f2b(b.x), f2b(b.y)), pack2(f2b(b.z), f2b(b.w)));
    }
    af = __builtin_bit_cast(bf16_8, p);
  }

  const f32x4 zz = {0.f, 0.f, 0.f, 0.f};
  f32x4 acc[16];
#pragma unroll
  for (int n = 0; n < 16; ++n) acc[n] = zz;
#pragma unroll
  for (int n = 0; n < 16; ++n)
    acc[n] = __builtin_amdgcn_mfma_f32_16x16x32_bf16(af, bfr[n], acc[n], 0, 0, 0);

#pragma unroll
  for (int n = 0; n < 16; ++n) {
    float bb = lin_b[n * 16 + r16];
#pragma unroll
    for (int rg = 0; rg < 4; ++rg)
      sT[wv][quad * 4 + rg][n * 16 + r16] = f2b(acc[n][rg] + bb);
  }
#pragma unroll
  for (int it = 0; it < 8; ++it) {
    int flat = it * 64 + lane;
    int row = flat >> 5, g = flat & 31;
    uint4 v = *(const uint4*)&sT[wv][row][g * 8];
    ntstore16(&eab[(size_t)(e0 + row) * D_ + g * 8], v);
  }
}

// ================= CSR build (per-launch) + gather aggregation =================
__global__ void k_zero(int* __restrict__ p, int n) {
  int i = blockIdx.x * 256 + threadIdx.x;
  if (i < n) p[i] = 0;
}
__global__ void k_hist(const int* __restrict__ adj, int* __restrict__ cnt) {
  int e = blockIdx.x * 256 + threadIdx.x;
  atomicAdd(&cnt[adj[E_ + e]], 1);
}
__global__ __launch_bounds__(1024) void k_scan(const int* __restrict__ cnt,
                                               int* __restrict__ off, int* __restrict__ cur) {
  __shared__ int ps[1024];
  int tid = threadIdx.x;
  int base = tid * 4;
  int a0 = cnt[base], a1 = cnt[base + 1], a2 = cnt[base + 2], a3 = cnt[base + 3];
  int tsum = a0 + a1 + a2 + a3;
  ps[tid] = tsum;
  __syncthreads();
  for (int st = 1; st < 1024; st <<= 1) {
    int v = (tid >= st) ? ps[tid - st] : 0;
    __syncthreads();
    ps[tid] += v;
    __syncthreads();
  }
  int excl = ps[tid] - tsum;
  int o0 = excl, o1 = excl + a0, o2 = o1 + a1, o3 = o2 + a2;
  off[base] = o0; off[base + 1] = o1; off[base + 2] = o2; off[base + 3] = o3;
  cur[base] = o0; cur[base + 1] = o1; cur[base + 2] = o2; cur[base + 3] = o3;
  if (tid == 1023) off[4096] = o3 + a3;
}
__global__ void k_bucket(const int* __restrict__ adj, int* __restrict__ cur,
                         int* __restrict__ perm) {
  int e = blockIdx.x * 256 + threadIdx.x;
  int p = atomicAdd(&cur[adj[E_ + e]], 1);
  perm[p] = e;
}
__global__ __launch_bounds__(256) void k_gather(
    const float* __restrict__ x, const int* __restrict__ adj,
    const unsigned short* __restrict__ eab, const float* __restrict__ nrm,
    const int* __restrict__ off, const int* __restrict__ perm,
    float* __restrict__ xout) {
  int n = blockIdx.x, t = threadIdx.x;
  int beg = off[n], end = off[n + 1];
  float acc = x[(size_t)n * D_ + t];
  int i = beg;
  for (; i + 1 < end; i += 2) {
    int e0 = perm[i], e1 = perm[i + 1];
    int s0 = adj[e0], s1 = adj[e1];
    float w0 = nrm[e0], w1 = nrm[e1];
    float xa = x[(size_t)s0 * D_ + t];
    float xb = x[(size_t)s1 * D_ + t];
    float ea0 = b2f(eab[(size_t)e0 * D_ + t]);
    float ea1 = b2f(eab[(size_t)e1 * D_ + t]);
    acc += w0 * (xa + ea0) + w1 * (xb + ea1);
  }
  if (i < end) {
    int e0 = perm[i];
    int s0 = adj[e0];
    float w0 = nrm[e0];
    acc += w0 * (x[(size_t)s0 * D_ + t] + b2f(eab[(size_t)e0 * D_ + t]));
  }
  xout[(size_t)n * D_ + t] = acc;
}

// ---------------- legacy scatter (fallback path) ----------------
__global__ __launch_bounds__(256) void k_scatter(
    const float* __restrict__ x, const int* __restrict__ adj,
    const float* __restrict__ dmap, const float* __restrict__ nrm,
    const float* __restrict__ lin_w, const float* __restrict__ lin_b,
    float* __restrict__ xout) {
  __shared__ float s_dm[4][DIN_];
  int te = threadIdx.x >> 6;
  int d4 = threadIdx.x & 63;
  int e  = blockIdx.x * 4 + te;
  if (d4 < DIN_) s_dm[te][d4] = dmap[(size_t)e * DIN_ + d4];
  __syncthreads();
  int vs = adj[e];
  int vd = adj[E_ + e];
  float w = nrm[e];
  int d = d4 * 4;
  float4 xs = *(const float4*)(x + (size_t)vs * D_ + d);
  float ea[4];
#pragma unroll
  for (int q = 0; q < 4; q++) {
    const float* lw = lin_w + (size_t)(d + q) * DIN_;
    float acc = lin_b[d + q];
#pragma unroll
    for (int k = 0; k < DIN_; k++) acc += s_dm[te][k] * lw[k];
    ea[q] = acc;
  }
  float* op = xout + (size_t)vd * D_ + d;
  atomicAdd(op + 0, w * (xs.x + ea[0]));
  atomicAdd(op + 1, w * (xs.y + ea[1]));
  atomicAdd(op + 2, w * (xs.z + ea[2]));
  atomicAdd(op + 3, w * (xs.w + ea[3]));
}

// ---------------- C[M,N] = A[M,K] @ B[N,K]^T + bias (fp32, fallback) ----------------
__global__ __launch_bounds__(256) void k_gemm_bt(
    const float* __restrict__ A, const float* __restrict__ B,
    const float* __restrict__ bias, float* __restrict__ C,
    int M, int Nn, int K) {
  __shared__ float sA[16][68];
  __shared__ float sB[16][68];
  int bm = blockIdx.y * 64, bn = blockIdx.x * 64;
  int tid = threadIdx.x;
  int tr = tid >> 4, tc = tid & 15;
  float acc[4][4] = {};
  for (int k0 = 0; k0 < K; k0 += 16) {
    for (int i = tid; i < 1024; i += 256) {
      int r = i >> 4, c = i & 15;
      sA[c][r] = A[(size_t)(bm + r) * K + k0 + c];
      sB[c][r] = B[(size_t)(bn + r) * K + k0 + c];
    }
    __syncthreads();
#pragma unroll
    for (int kk = 0; kk < 16; kk++) {
      float av[4], bv[4];
#pragma unroll
      for (int i = 0; i < 4; i++) av[i] = sA[kk][tr * 4 + i];
#pragma unroll
      for (int j = 0; j < 4; j++) bv[j] = sB[kk][tc * 4 + j];
#pragma unroll
      for (int i = 0; i < 4; i++)
#pragma unroll
        for (int j = 0; j < 4; j++) acc[i][j] += av[i] * bv[j];
    }
    __syncthreads();
  }
#pragma unroll
  for (int i = 0; i < 4; i++) {
    int r = bm + tr * 4 + i;
#pragma unroll
    for (int j = 0; j < 4; j++) {
      int c = bn + tc * 4 + j;
      C[(size_t)r * Nn + c] = acc[i][j] + bias[c];
    }
  }
}

// ---------------- qkv proj via MFMA: bf16 in, fp32 qkv out ----------------
__global__ __launch_bounds__(256) void k_qkv_mfma(
    const unsigned short* __restrict__ inb, const unsigned short* __restrict__ wqb,
    const float* __restrict__ ipb, float* __restrict__ qkv) {
  __shared__ unsigned short sA[128][72];
  __shared__ unsigned short sB[128][72];
  const int b   = blockIdx.x;
  const int j0  = (b % 6) * 128;
  const int m0  = (b / 6) * 128;
  const int tid = threadIdx.x;
  const int lane = tid & 63, wv = tid >> 6;
  const int r16  = lane & 15, quad = lane >> 4;
  const int sr   = tid >> 1, sh = (tid & 1) * 32;

  const unsigned short* ra = inb + (size_t)(m0 + sr) * D_;
  const unsigned short* rb = wqb + (size_t)(j0 + sr) * D_;

  const f32x4 zz = {0.f, 0.f, 0.f, 0.f};
  f32x4 acc[2][8];
#pragma unroll
  for (int m = 0; m < 2; ++m)
#pragma unroll
    for (int n = 0; n < 8; ++n) acc[m][n] = zz;

  for (int ki = 0; ki < 4; ++ki) {
    __syncthreads();
    {
      const uint4* s    = (const uint4*)(ra + ki * 64 + sh);
      const uint4* bsrc = (const uint4*)(rb + ki * 64 + sh);
      uint4* da = (uint4*)&sA[sr][sh];
      uint4* db = (uint4*)&sB[sr][sh];
#pragma unroll
      for (int i = 0; i < 4; ++i) { da[i] = s[i]; db[i] = bsrc[i]; }
    }
    __syncthreads();
#pragma unroll
    for (int kk = 0; kk < 2; ++kk) {
      bf16_8 a0 = frag16(&sA[wv * 32 + r16][kk * 32 + quad * 8]);
      bf16_8 a1 = frag16(&sA[wv * 32 + 16 + r16][kk * 32 + quad * 8]);
#pragma unroll
      for (int n = 0; n < 8; ++n) {
        bf16_8 bf = frag16(&sB[n * 16 + r16][kk * 32 + quad * 8]);
        acc[0][n] = __builtin_amdgcn_mfma_f32_16x16x32_bf16(a0, bf, acc[0][n], 0, 0, 0);
        acc[1][n] = __builtin_amdgcn_mfma_f32_16x16x32_bf16(a1, bf, acc[1][n], 0, 0, 0);
      }
    }
  }
#pragma unroll
  for (int m = 0; m < 2; ++m)
#pragma unroll
    for (int n = 0; n < 8; ++n) {
      int col = j0 + n * 16 + r16;
      float bb = ipb[col];
#pragma unroll
      for (int rg = 0; rg < 4; ++rg) {
        int row = m0 + wv * 32 + m * 16 + quad * 4 + rg;
        qkv[(size_t)row * D3_ + col] = acc[m][n][rg] + bb;
      }
    }
}

// ---------------- out_proj via MFMA: hgl = attob @ opwb^T + opb; hgb = bf16 ----
__global__ __launch_bounds__(256) void k_outproj_mfma(
    const unsigned short* __restrict__ attob, const unsigned short* __restrict__ opwb,
    const float* __restrict__ opb, float* __restrict__ hgl,
    unsigned short* __restrict__ hgb) {
  __shared__ unsigned short sA[128][72];
  __shared__ unsigned short sB[128][72];
  const int b   = blockIdx.x;
  const int j0  = (b & 1) * 128;
  const int m0  = (b >> 1) * 128;
  const int tid = threadIdx.x;
  const int lane = tid & 63, wv = tid >> 6;
  const int r16  = lane & 15, quad = lane >> 4;
  const int sr   = tid >> 1, sh = (tid & 1) * 32;

  const unsigned short* ra = attob + (size_t)(m0 + sr) * D_;
  const unsigned short* rb = opwb + (size_t)(j0 + sr) * D_;

  const f32x4 zz = {0.f, 0.f, 0.f, 0.f};
  f32x4 acc[2][8];
#pragma unroll
  for (int m = 0; m < 2; ++m)
#pragma unroll
    for (int n = 0; n < 8; ++n) acc[m][n] = zz;

  for (int ki = 0; ki < 4; ++ki) {
    __syncthreads();
    {
      const uint4* s    = (const uint4*)(ra + ki * 64 + sh);
      const uint4* bsrc = (const uint4*)(rb + ki * 64 + sh);
      uint4* da = (uint4*)&sA[sr][sh];
      uint4* db = (uint4*)&sB[sr][sh];
#pragma unroll
      for (int i = 0; i < 4; ++i) { da[i] = s[i]; db[i] = bsrc[i]; }
    }
    __syncthreads();
#pragma unroll
    for (int kk = 0; kk < 2; ++kk) {
      bf16_8 a0 = frag16(&sA[wv * 32 + r16][kk * 32 + quad * 8]);
      bf16_8 a1 = frag16(&sA[wv * 32 + 16 + r16][kk * 32 + quad * 8]);
#pragma unroll
      for (int n = 0; n < 8; ++n) {
        bf16_8 bf = frag16(&sB[n * 16 + r16][kk * 32 + quad * 8]);
        acc[0][n] = __builtin_amdgcn_mfma_f32_16x16x32_bf16(a0, bf, acc[0][n], 0, 0, 0);
        acc[1][n] = __builtin_amdgcn_mfma_f32_16x16x32_bf16(a1, bf, acc[1][n], 0, 0, 0);
      }
    }
  }
#pragma unroll
  for (int m = 0; m < 2; ++m)
#pragma unroll
    for (int n = 0; n < 8; ++n) {
      int col = j0 + n * 16 + r16;
      float bb = opb[col];
#pragma unroll
      for (int rg = 0; rg < 4; ++rg) {
        int row = m0 + wv * 32 + m * 16 + quad * 4 + rg;
        float v = acc[m][n][rg] + bb;
        size_t idx = (size_t)row * D_ + col;
        hgl[idx] = v;
        hgb[idx] = f2b(v);
      }
    }
}

// ---------------- final combine via MFMA ----------------
__global__ __launch_bounds__(256) void k_final_mfma(
    const unsigned short* __restrict__ xbp, const unsigned short* __restrict__ h0b,
    const unsigned short* __restrict__ hgb,
    const unsigned short* __restrict__ wlT, const unsigned short* __restrict__ wgT,
    const float* __restrict__ hl, const float* __restrict__ hg, const float* __restrict__ h0,
    const float* __restrict__ alpha_p, const void* lamda_p, const void* l_p,
    float* __restrict__ out) {
  __shared__ unsigned short sA[128][72];
  __shared__ unsigned short sB[128][72];
  const int b   = blockIdx.x;
  const int j0  = (b & 1) * 128;
  const int m0  = (b >> 1) * 128;
  const int tid = threadIdx.x;
  const int lane = tid & 63, wv = tid >> 6;
  const int r16  = lane & 15, quad = lane >> 4;
  const int sr   = tid >> 1, sh = (tid & 1) * 32;

  const f32x4 zz = {0.f, 0.f, 0.f, 0.f};
  f32x4 acc[2][8];
#pragma unroll
  for (int m = 0; m < 2; ++m)
#pragma unroll
    for (int n = 0; n < 8; ++n) acc[m][n] = zz;

  const size_t arow = (size_t)(m0 + sr) * D_;
  const size_t brow = (size_t)(j0 + sr) * 512;

  for (int ki = 0; ki < 16; ++ki) {
    __syncthreads();
    {
      const int gc = ki * 64 + sh;
      const unsigned short* ap =
          (gc < 256) ? xbp + arow + gc
        : (gc < 512) ? h0b + arow + (gc - 256)
        : (gc < 768) ? hgb + arow + (gc - 512)
                     : h0b + arow + (gc - 768);
      const unsigned short* bp = (gc < 512) ? wlT + brow + gc : wgT + brow + (gc - 512);
      const uint4* s    = (const uint4*)ap;
      const uint4* bsrc = (const uint4*)bp;
      uint4* da = (uint4*)&sA[sr][sh];
      uint4* db = (uint4*)&sB[sr][sh];
#pragma unroll
      for (int i = 0; i < 4; ++i) { da[i] = s[i]; db[i] = bsrc[i]; }
    }
    __syncthreads();
#pragma unroll
    for (int kk = 0; kk < 2; ++kk) {
      bf16_8 a0 = frag16(&sA[wv * 32 + r16][kk * 32 + quad * 8]);
      bf16_8 a1 = frag16(&sA[wv * 32 + 16 + r16][kk * 32 + quad * 8]);
#pragma unroll
      for (int n = 0; n < 8; ++n) {
        bf16_8 bf = frag16(&sB[n * 16 + r16][kk * 32 + quad * 8]);
        acc[0][n] = __builtin_amdgcn_mfma_f32_16x16x32_bf16(a0, bf, acc[0][n], 0, 0, 0);
        acc[1][n] = __builtin_amdgcn_mfma_f32_16x16x32_bf16(a1, bf, acc[1][n], 0, 0, 0);
      }
    }
  }
  float theta = fminf(1.f, logf(scalar_as_float(lamda_p) / scalar_as_float(l_p) + 1.f));
  float a = alpha_p[0];
  float omt = 1.f - theta;
#pragma unroll
  for (int m = 0; m < 2; ++m)
#pragma unroll
    for (int n = 0; n < 8; ++n) {
      int col = j0 + n * 16 + r16;
#pragma unroll
      for (int rg = 0; rg < 4; ++rg) {
        int row = m0 + wv * 32 + m * 16 + quad * 4 + rg;
        size_t idx = (size_t)row * D_ + col;
        out[idx] = theta * acc[m][n][rg] +
                   omt * ((1.f - a) * (hl[idx] + hg[idx]) + 2.f * a * h0[idx]);
      }
    }
}

// ---------------- qkv split: fp32 [N,768] -> bf16 Qb/Kb [h][n][128] ----------------
__global__ void k_qk2b(const float* __restrict__ qkv,
                       unsigned short* __restrict__ Qb, unsigned short* __restrict__ Kb) {
  int off = (blockIdx.x * 256 + threadIdx.x) * 8;   // over N*512
  int n = off >> 9, c = off & 511;
  const float* src = qkv + (size_t)n * D3_ + c;     // Q cols 0..255, K cols 256..511
  float4 a = *(const float4*)src;
  float4 b = *(const float4*)(src + 4);
  uint4 p = {pack2(f2b(a.x), f2b(a.y)), pack2(f2b(a.z), f2b(a.w)),
             pack2(f2b(b.x), f2b(b.y)), pack2(f2b(b.z), f2b(b.w))};
  int cc = c & 255;
  int hh = cc >> 7, d = cc & 127;
  unsigned short* dst = (c < 256 ? Qb : Kb) + (size_t)hh * N_ * HD_ + (size_t)n * HD_ + d;
  *(uint4*)dst = p;
}

// ---------------- V transpose: fp32 qkv V-cols -> bf16 Vt [h][128][N] ----------------
__global__ __launch_bounds__(256) void k_v2t(const float* __restrict__ qkv,
                                             unsigned short* __restrict__ Vt) {
  __shared__ unsigned short sv[64][136];
  int h = blockIdx.y;
  int n0 = blockIdx.x * 64;
  int tid = threadIdx.x;
#pragma unroll
  for (int it = 0; it < 4; ++it) {
    int off = (tid + it * 256) * 8;
    int r = off >> 7, d = off & 127;
    const float* src = qkv + (size_t)(n0 + r) * D3_ + 2 * D_ + h * HD_ + d;
    float4 a = *(const float4*)src;
    float4 b = *(const float4*)(src + 4);
    uint4 p = {pack2(f2b(a.x), f2b(a.y)), pack2(f2b(a.z), f2b(a.w)),
               pack2(f2b(b.x), f2b(b.y)), pack2(f2b(b.z), f2b(b.w))};
    *(uint4*)&sv[r][d] = p;
  }
  __syncthreads();
#pragma unroll
  for (int it = 0; it < 4; ++it) {
    int off = (tid + it * 256) * 8;
    int d = off >> 6, k = off & 63;
    unsigned short t[8];
#pragma unroll
    for (int j = 0; j < 8; ++j) t[j] = sv[k + j][d];
    uint4 p = {pack2(t[0], t[1]), pack2(t[2], t[3]),
               pack2(t[4], t[5]), pack2(t[6], t[7])};
    *(uint4*)(Vt + (size_t)h * HD_ * N_ + (size_t)d * N_ + n0 + k) = p;
  }
}

// ---------------- MFMA flash attention, H=2, HD=128 (dual fp32+bf16 out) ----------------
__global__ __launch_bounds__(256) void k_attn_mfma(
    const unsigned short* __restrict__ Qb, const unsigned short* __restrict__ Kb,
    const unsigned short* __restrict__ Vt, float* __restrict__ o_out,
    unsigned short* __restrict__ ob) {
  __shared__ unsigned short sK[64][136];   // keys x dims (+8 pad)
  __shared__ unsigned short sV[128][72];   // dims x keys (+8 pad)
  __shared__ float          sS[16][68];    // scores
  __shared__ unsigned short sP[16][72];    // probs bf16 (A-frag layout)
  __shared__ float sm[16], sl[16], sa[16];

  const int tid  = threadIdx.x;
  const int h    = blockIdx.y;
  const int q0   = blockIdx.x * 16;
  const int lane = tid & 63;
  const int wv   = tid >> 6;
  const int r16  = lane & 15;
  const int quad = lane >> 4;

  bf16_8 qf[4];
#pragma unroll
  for (int kk = 0; kk < 4; ++kk)
    qf[kk] = frag16(Qb + (size_t)h * N_ * HD_ + (size_t)(q0 + r16) * HD_ + kk * 32 + quad * 8);

  if (tid < 16) { sm[tid] = -1e30f; sl[tid] = 0.f; }

  const f32x4 zz = {0.f, 0.f, 0.f, 0.f};
  f32x4 o0 = zz, o1 = zz;

  const unsigned short* Kh = Kb + (size_t)h * N_ * HD_;
  const unsigned short* Vh = Vt + (size_t)h * HD_ * N_;

  for (int c0 = 0; c0 < N_; c0 += 64) {
    __syncthreads();
#pragma unroll
    for (int it = 0; it < 4; ++it) {
      int off = (tid + it * 256) * 8;
      int key = off >> 7, d = off & 127;
      *(uint4*)&sK[key][d] = *(const uint4*)(Kh + (size_t)(c0 + key) * HD_ + d);
    }
#pragma unroll
    for (int it = 0; it < 4; ++it) {
      int off = (tid + it * 256) * 8;
      int d = off >> 6, k = off & 63;
      *(uint4*)&sV[d][k] = *(const uint4*)(Vh + (size_t)d * N_ + c0 + k);
    }
    __syncthreads();
    f32x4 s = zz;
#pragma unroll
    for (int kk = 0; kk < 4; ++kk) {
      bf16_8 bf = frag16(&sK[wv * 16 + r16][kk * 32 + quad * 8]);
      s = __builtin_amdgcn_mfma_f32_16x16x32_bf16(qf[kk], bf, s, 0, 0, 0);
    }
    const float sc = 0.08838834764831845f;   // 1/sqrt(128)
#pragma unroll
    for (int r = 0; r < 4; ++r)
      sS[quad * 4 + r][wv * 16 + r16] = s[r] * sc;
    __syncthreads();
    {
      int row = tid >> 4, i = tid & 15;
      float4 v = *(const float4*)&sS[row][i * 4];
      float mx = fmaxf(fmaxf(v.x, v.y), fmaxf(v.z, v.w));
#pragma unroll
      for (int m = 1; m <= 8; m <<= 1) mx = fmaxf(mx, __shfl_xor(mx, m));
      float mo = sm[row];
      float mn = fmaxf(mo, mx);
      float p0 = __expf(v.x - mn), p1 = __expf(v.y - mn);
      float p2 = __expf(v.z - mn), p3 = __expf(v.w - mn);
      float ps = p0 + p1 + p2 + p3;
#pragma unroll
      for (int m = 1; m <= 8; m <<= 1) ps += __shfl_xor(ps, m);
      uint2 pk = {pack2(f2b(p0), f2b(p1)), pack2(f2b(p2), f2b(p3))};
      *(uint2*)&sP[row][i * 4] = pk;
      if (i == 0) {
        float al = __expf(mo - mn);
        sl[row] = sl[row] * al + ps;
        sm[row] = mn;
        sa[row] = al;
      }
    }
    __syncthreads();
    {
      float al0 = sa[quad * 4 + 0], al1 = sa[quad * 4 + 1];
      float al2 = sa[quad * 4 + 2], al3 = sa[quad * 4 + 3];
      o0[0] *= al0; o0[1] *= al1; o0[2] *= al2; o0[3] *= al3;
      o1[0] *= al0; o1[1] *= al1; o1[2] *= al2; o1[3] *= al3;
#pragma unroll
      for (int kk = 0; kk < 2; ++kk) {
        bf16_8 pa = frag16(&sP[r16][kk * 32 + quad * 8]);
        bf16_8 v0 = frag16(&sV[wv * 32 + r16][kk * 32 + quad * 8]);
        bf16_8 v1 = frag16(&sV[wv * 32 + 16 + r16][kk * 32 + quad * 8]);
        o0 = __builtin_amdgcn_mfma_f32_16x16x32_bf16(pa, v0, o0, 0, 0, 0);
        o1 = __builtin_amdgcn_mfma_f32_16x16x32_bf16(pa, v1, o1, 0, 0, 0);
      }
    }
  }
  {
    float i0 = 1.f / sl[quad * 4 + 0], i1 = 1.f / sl[quad * 4 + 1];
    float i2 = 1.f / sl[quad * 4 + 2], i3 = 1.f / sl[quad * 4 + 3];
    float vv[8];
    vv[0] = o0[0] * i0; vv[1] = o0[1] * i1; vv[2] = o0[2] * i2; vv[3] = o0[3] * i3;
    vv[4] = o1[0] * i0; vv[5] = o1[1] * i1; vv[6] = o1[2] * i2; vv[7] = o1[3] * i3;
#pragma unroll
    for (int g = 0; g < 2; ++g)
#pragma unroll
      for (int rg = 0; rg < 4; ++rg) {
        size_t idx = (size_t)(q0 + quad * 4 + rg) * D_ + h * HD_ + wv * 32 + g * 16 + r16;
        float v = vv[g * 4 + rg];
        o_out[idx] = v;
        ob[idx] = f2b(v);
      }
  }
}

// ---------------- final combine (fp32, fallback) ----------------
__global__ __launch_bounds__(256) void k_final(
    const float* __restrict__ hl, const float* __restrict__ hg, const float* __restrict__ h0,
    const float* __restrict__ Wl, const float* __restrict__ Wg,
    const float* __restrict__ alpha_p, const void* lamda_p, const void* l_p,
    float* __restrict__ out) {
  __shared__ float sA[16][68];
  __shared__ float sB[16][68];
  float theta = fminf(1.f, logf(scalar_as_float(lamda_p) / scalar_as_float(l_p) + 1.f));
  float a = alpha_p[0];
  int bm = blockIdx.y * 64, bn = blockIdx.x * 64;
  int tid = threadIdx.x, tr = tid >> 4, tc = tid & 15;
  float acc[4][4] = {};
  for (int k0 = 0; k0 < 1024; k0 += 16) {
    for (int i = tid; i < 1024; i += 256) {
      int r = i >> 4, c = i & 15;
      int k = k0 + c;
      const float* src = (k < 256) ? hl : (k < 512) ? h0 : (k < 768) ? hg : h0;
      sA[c][r] = src[(size_t)(bm + r) * 256 + (k & 255)];
    }
    for (int i = tid; i < 1024; i += 256) {
      int kk = i >> 6, j = i & 63;
      int k = k0 + kk;
      const float* Bp = (k < 512) ? (Wl + (size_t)k * 256) : (Wg + (size_t)(k - 512) * 256);
      sB[kk][j] = Bp[bn + j];
    }
    __syncthreads();
#pragma unroll
    for (int kk = 0; kk < 16; kk++) {
      float av[4], bv[4];
#pragma unroll
      for (int i = 0; i < 4; i++) av[i] = sA[kk][tr * 4 + i];
#pragma unroll
      for (int j = 0; j < 4; j++) bv[j] = sB[kk][tc * 4 + j];
#pragma unroll
      for (int i = 0; i < 4; i++)
#pragma unroll
        for (int j = 0; j < 4; j++) acc[i][j] += av[i] * bv[j];
    }
    __syncthreads();
  }
  float omt = 1.f - theta;
#pragma unroll
  for (int i = 0; i < 4; i++) {
    int r = bm + tr * 4 + i;
#pragma unroll
    for (int j = 0; j < 4; j++) {
      int c = bn + tc * 4 + j;
      size_t idx = (size_t)r * 256 + c;
      out[idx] = theta * acc[i][j] + omt * ((1.f - a) * (hl[idx] + hg[idx]) + 2.f * a * h0[idx]);
    }
  }
}

// ================= edge MLP as tiled GEMMs (fast path) =================
// GEMM1: h3[E,768] @ wb1^T -> gelu -> t1[E,512] bf16. 128x128 tile, BK=64.
__global__ __launch_bounds__(256) void k_mlp_gemm1(
    const unsigned short* __restrict__ xb, const int* __restrict__ adj,
    const unsigned short* __restrict__ eab, const unsigned short* __restrict__ wb1,
    const float* __restrict__ b1, unsigned short* __restrict__ t1) {
  __shared__ unsigned short lA[16 * 512];   // 16 A-frags x 1KB
  __shared__ unsigned short lB[16 * 512];   // 16 B-frags x 1KB
  const int b    = blockIdx.x;
  const int j0   = ((b >> 3) & 3) * 128;
  const int e0   = (((b >> 5) << 3) | (b & 7)) * 128;
  const int tid  = threadIdx.x;
  const int lane = tid & 63, wv = tid >> 6;
  const int r16  = lane & 15, quad = lane >> 4;

  const int row0 = e0 + wv * 32 + r16;
  const int row1 = row0 + 16;
  const int vs0 = adj[row0], vs1 = adj[row1];
  const int vd0 = adj[E_ + row0], vd1 = adj[E_ + row1];
  const unsigned short* pb0 = wb1 + (size_t)(j0 + (wv * 2 + 0) * 16 + r16) * 768 + quad * 8;
  const unsigned short* pb1 = wb1 + (size_t)(j0 + (wv * 2 + 1) * 16 + r16) * 768 + quad * 8;

  const f32x4 zz = {0.f, 0.f, 0.f, 0.f};
  f32x4 acc[2][8];
#pragma unroll
  for (int m = 0; m < 2; ++m)
#pragma unroll
    for (int n = 0; n < 8; ++n) acc[m][n] = zz;

  for (int ki = 0; ki < 12; ++ki) {
    __syncthreads();
    {
      const int seg = ki >> 2;
      const int col = (ki & 3) * 64 + quad * 8;
      const unsigned short* ap0;
      const unsigned short* ap1;
      if (seg == 1) {
        ap0 = eab + (size_t)row0 * D_;
        ap1 = eab + (size_t)row1 * D_;
      } else {
        int n0 = (seg == 0) ? vs0 : vd0;
        int n1 = (seg == 0) ? vs1 : vd1;
        ap0 = xb + (size_t)n0 * D_;
        ap1 = xb + (size_t)n1 * D_;
      }
#pragma unroll
      for (int kk = 0; kk < 2; ++kk) {
        gl2lds16(ap0 + col + kk * 32, &lA[(wv * 4 + kk) * 512]);
        gl2lds16(ap1 + col + kk * 32, &lA[(wv * 4 + 2 + kk) * 512]);
        gl2lds16(pb0 + ki * 64 + kk * 32, &lB[((wv * 2 + 0) * 2 + kk) * 512]);
        gl2lds16(pb1 + ki * 64 + kk * 32, &lB[((wv * 2 + 1) * 2 + kk) * 512]);
      }
    }
    __builtin_amdgcn_s_waitcnt(0);
    __syncthreads();
#pragma unroll
    for (int kk = 0; kk < 2; ++kk) {
      bf16_8 a0 = frag16(&lA[(wv * 4 + kk) * 512 + lane * 8]);
      bf16_8 a1 = frag16(&lA[(wv * 4 + 2 + kk) * 512 + lane * 8]);
#pragma unroll
      for (int n = 0; n < 8; ++n) {
        bf16_8 bf = frag16(&lB[(n * 2 + kk) * 512 + lane * 8]);
        acc[0][n] = __builtin_amdgcn_mfma_f32_16x16x32_bf16(a0, bf, acc[0][n], 0, 0, 0);
        acc[1][n] = __builtin_amdgcn_mfma_f32_16x16x32_bf16(a1, bf, acc[1][n], 0, 0, 0);
      }
    }
  }
  __syncthreads();
  unsigned short* reg = ((wv < 2) ? lA : lB) + (wv & 1) * 4096;
  float bias[8];
#pragma unroll
  for (int n = 0; n < 8; ++n) bias[n] = b1[j0 + n * 16 + r16];
#pragma unroll
  for (int m = 0; m < 2; ++m)
#pragma unroll
    for (int n = 0; n < 8; ++n)
#pragma unroll
      for (int rg = 0; rg < 4; ++rg)
        reg[(m * 16 + quad * 4 + rg) * 128 + n * 16 + r16] =
            f2b(gelu_exact(acc[m][n][rg] + bias[n]));
#pragma unroll
  for (int it = 0; it < 8; ++it) {
    int flat = it * 64 + lane;
    int row = flat >> 4, c16 = flat & 15;
    uint4 v = *(const uint4*)&reg[row * 128 + c16 * 8];
    ntstore16(&t1[(size_t)(e0 + wv * 32 + row) * 512 + j0 + c16 * 8], v);
  }
}

// GEMM2+3 fused: t1 @ wb2^T -> gelu -> t2 (LDS only) -> @ wb3^T -> dmo.
// 64 edges/block, 4 waves x 16 rows x N=256 (acc[16] = 64 VGPRs).
__global__ __launch_bounds__(256) void k_mlp_gemm23(
    const unsigned short* __restrict__ t1, const unsigned short* __restrict__ wb2,
    const float* __restrict__ b2, const unsigned short* __restrict__ wb3,
    const float* __restrict__ b3, float* __restrict__ dmo) {
  __shared__ unsigned short lA[8 * 512];    // 8 KB
  __shared__ unsigned short lB[32 * 512];   // 32 KB
  const int e0   = blockIdx.x * 64;
  const int tid  = threadIdx.x;
  const int lane = tid & 63, wv = tid >> 6;
  const int r16  = lane & 15, quad = lane >> 4;

  const int row = e0 + wv * 16 + r16;
  const unsigned short* pa = t1 + (size_t)row * 512 + quad * 8;

  const f32x4 zz = {0.f, 0.f, 0.f, 0.f};
  f32x4 acc[16];
#pragma unroll
  for (int n = 0; n < 16; ++n) acc[n] = zz;

  for (int ki = 0; ki < 8; ++ki) {
    __syncthreads();
    {
#pragma unroll
      for (int kk = 0; kk < 2; ++kk) {
        gl2lds16(pa + ki * 64 + kk * 32, &lA[(wv * 2 + kk) * 512]);
#pragma unroll
        for (int i = 0; i < 4; ++i) {
          int n = wv * 4 + i;
          gl2lds16(wb2 + (size_t)(n * 16 + r16) * 512 + ki * 64 + kk * 32 + quad * 8,
                   &lB[(n * 2 + kk) * 512]);
        }
      }
    }
    __builtin_amdgcn_s_waitcnt(0);
    __syncthreads();
#pragma unroll
    for (int kk = 0; kk < 2; ++kk) {
      bf16_8 a = frag16(&lA[(wv * 2 + kk) * 512 + lane * 8]);
#pragma unroll
      for (int n = 0; n < 16; ++n) {
        bf16_8 bf = frag16(&lB[(n * 2 + kk) * 512 + lane * 8]);
        acc[n] = __builtin_amdgcn_mfma_f32_16x16x32_bf16(a, bf, acc[n], 0, 0, 0);
      }
    }
  }
  __syncthreads();   // all compute reads done before lB reuse
  unsigned short* reg = lB + wv * 4096;   // wave-private [16][256]
#pragma unroll
  for (int n = 0; n < 16; ++n) {
    float bb = b2[n * 16 + r16];
#pragma unroll
    for (int rg = 0; rg < 4; ++rg)
      reg[(quad * 4 + rg) * 256 + n * 16 + r16] = f2b(gelu_exact(acc[n][rg] + bb));
  }
  f32x4 acc3 = zz;
#pragma unroll
  for (int ks = 0; ks < 8; ++ks) {
    bf16_8 a = frag16(&reg[r16 * 256 + ks * 32 + quad * 8]);
    bf16_8 b = frag16(wb3 + (size_t)r16 * 256 + ks * 32 + quad * 8);
    acc3 = __builtin_amdgcn_mfma_f32_16x16x32_bf16(a, b, acc3, 0, 0, 0);
  }
  float bb = b3[r16];
#pragma unroll
  for (int rg = 0; rg < 4; ++rg)
    dmo[(size_t)(e0 + wv * 16 + quad * 4 + rg) * DIN_ + r16] = acc3[rg] + bb;
}

// ---------------- fused edge MLP (fallback path) ----------------
__global__ __launch_bounds__(256, 3) void k_edge_mlp_mfma(
    const float* __restrict__ xout, const int* __restrict__ adj,
    const float* __restrict__ dmap,
    const float* __restrict__ lin_w, const float* __restrict__ lin_b,
    const unsigned short* __restrict__ wb1, const float* __restrict__ b1,
    const unsigned short* __restrict__ wb2, const float* __restrict__ b2,
    const unsigned short* __restrict__ wb3, const float* __restrict__ b3,
    float* __restrict__ dmo) {
  __shared__ unsigned short sLo[8448];
  __shared__ unsigned short sT1[32][520];
  unsigned short (*sA)[136]  = (unsigned short(*)[136])sLo;
  unsigned short (*sT2)[264] = (unsigned short(*)[264])sLo;

  const int tid  = threadIdx.x;
  const int e0   = blockIdx.x * 32;
  const int lane = tid & 63;
  const int wv   = tid >> 6;
  const int r16  = lane & 15;
  const int quad = lane >> 4;

  const int sr = tid >> 3;
  const int t8 = tid & 7;
  const int se = e0 + sr;
  const int vsrc = adj[se];
  const int vdst = adj[E_ + se];

  float4 pf0, pf1, pf2, pf3;
  float4 dm0, dm1, dm2, dm3;
  {
    const float4* sp = (const float4*)(xout + (size_t)vsrc * D_ + t8 * 16);
    pf0 = sp[0]; pf1 = sp[1]; pf2 = sp[2]; pf3 = sp[3];
  }

  const f32x4 zz = {0.f, 0.f, 0.f, 0.f};
  f32x4 acc1[8][2];
#pragma unroll
  for (int i = 0; i < 8; ++i) { acc1[i][0] = zz; acc1[i][1] = zz; }

  for (int c = 0; c < 6; ++c) {
    const int k0 = c * 128;
    __syncthreads();
    {
      unsigned short tmp[16];
      if (c == 2 || c == 3) {
        int jb = (c - 2) * 128 + t8 * 16;
#pragma unroll
        for (int j = 0; j < 16; ++j) {
          const float4* lw = (const float4*)(lin_w + (size_t)(jb + j) * DIN_);
          float4 w0 = lw[0], w1 = lw[1], w2 = lw[2], w3 = lw[3];
          float acc = lin_b[jb + j];
          acc += dm0.x * w0.x + dm0.y * w0.y + dm0.z * w0.z + dm0.w * w0.w;
          acc += dm1.x * w1.x + dm1.y * w1.y + dm1.z * w1.z + dm1.w * w1.w;
          acc += dm2.x * w2.x + dm2.y * w2.y + dm2.z * w2.z + dm2.w * w2.w;
          acc += dm3.x * w3.x + dm3.y * w3.y + dm3.z * w3.z + dm3.w * w3.w;
          tmp[j] = f2b(acc);
        }
      } else {
        tmp[0]  = f2b(pf0.x); tmp[1]  = f2b(pf0.y); tmp[2]  = f2b(pf0.z); tmp[3]  = f2b(pf0.w);
        tmp[4]  = f2b(pf1.x); tmp[5]  = f2b(pf1.y); tmp[6]  = f2b(pf1.z); tmp[7]  = f2b(pf1.w);
        tmp[8]  = f2b(pf2.x); tmp[9]  = f2b(pf2.y); tmp[10] = f2b(pf2.z); tmp[11] = f2b(pf2.w);
        tmp[12] = f2b(pf3.x); tmp[13] = f2b(pf3.y); tmp[14] = f2b(pf3.z); tmp[15] = f2b(pf3.w);
      }
      unsigned short* dstp = &sA[sr][t8 * 16];
      uint4 q0v = {pack2(tmp[0], tmp[1]),   pack2(tmp[2], tmp[3]),
                   pack2(tmp[4], tmp[5]),   pack2(tmp[6], tmp[7])};
      uint4 q1v = {pack2(tmp[8], tmp[9]),   pack2(tmp[10], tmp[11]),
                   pack2(tmp[12], tmp[13]), pack2(tmp[14], tmp[15])};
      *(uint4*)(dstp) = q0v;
      *(uint4*)(dstp + 8) = q1v;
    }
    if (c == 0) {
      const float4* sp = (const float4*)(xout + (size_t)vsrc * D_ + 128 + t8 * 16);
      pf0 = sp[0]; pf1 = sp[1]; pf2 = sp[2]; pf3 = sp[3];
    } else if (c == 1) {
      const float4* dp = (const float4*)(dmap + (size_t)se * DIN_);
      dm0 = ntload4(dp); dm1 = ntload4(dp + 1); dm2 = ntload4(dp + 2); dm3 = ntload4(dp + 3);
    } else if (c == 3) {
      const float4* sp = (const float4*)(xout + (size_t)vdst * D_ + t8 * 16);
      pf0 = sp[0]; pf1 = sp[1]; pf2 = sp[2]; pf3 = sp[3];
    } else if (c == 4) {
      const float4* sp = (const float4*)(xout + (size_t)vdst * D_ + 128 + t8 * 16);
      pf0 = sp[0]; pf1 = sp[1]; pf2 = sp[2]; pf3 = sp[3];
    }
    __syncthreads();
#pragma unroll
    for (int kk = 0; kk < 4; ++kk) {
      bf16_8 a0 = frag16(&sA[r16][kk * 32 + quad * 8]);
      bf16_8 a1 = frag16(&sA[16 + r16][kk * 32 + quad * 8]);
#pragma unroll
      for (int i = 0; i < 8; ++i) {
        const unsigned short* bp =
            wb1 + (size_t)(wv * 128 + i * 16 + r16) * 768 + k0 + kk * 32 + quad * 8;
        bf16_8 bf = frag16(bp);
        acc1[i][0] = __builtin_amdgcn_mfma_f32_16x16x32_bf16(a0, bf, acc1[i][0], 0, 0, 0);
        acc1[i][1] = __builtin_amdgcn_mfma_f32_16x16x32_bf16(a1, bf, acc1[i][1], 0, 0, 0);
      }
    }
  }
#pragma unroll
  for (int i = 0; i < 8; ++i) {
    int col = wv * 128 + i * 16 + r16;
    float bb = b1[col];
#pragma unroll
    for (int m = 0; m < 2; ++m)
#pragma unroll
      for (int r = 0; r < 4; ++r) {
        int row = m * 16 + quad * 4 + r;
        sT1[row][col] = f2b(gelu_exact(acc1[i][m][r] + bb));
      }
  }
  __syncthreads();

  f32x4 acc2[4][2];
#pragma unroll
  for (int i = 0; i < 4; ++i) { acc2[i][0] = zz; acc2[i][1] = zz; }
#pragma unroll 4
  for (int ks = 0; ks < 16; ++ks) {
    bf16_8 a0 = frag16(&sT1[r16][ks * 32 + quad * 8]);
    bf16_8 a1 = frag16(&sT1[16 + r16][ks * 32 + quad * 8]);
#pragma unroll
    for (int i = 0; i < 4; ++i) {
      const unsigned short* bp =
          wb2 + (size_t)(wv * 64 + i * 16 + r16) * 512 + ks * 32 + quad * 8;
      bf16_8 bf = frag16(bp);
      acc2[i][0] = __builtin_amdgcn_mfma_f32_16x16x32_bf16(a0, bf, acc2[i][0], 0, 0, 0);
      acc2[i][1] = __builtin_amdgcn_mfma_f32_16x16x32_bf16(a1, bf, acc2[i][1], 0, 0, 0);
    }
  }
#pragma unroll
  for (int i = 0; i < 4; ++i) {
    int col = wv * 64 + i * 16 + r16;
    float bb = b2[col];
#pragma unroll
    for (int m = 0; m < 2; ++m)
#pragma unroll
      for (int r = 0; r < 4; ++r) {
        int row = m * 16 + quad * 4 + r;
        sT2[row][col] = f2b(gelu_exact(acc2[i][m][r] + bb));
      }
  }
  __syncthreads();

  if (wv < 2) {
    f32x4 acc3 = zz;
#pragma unroll
    for (int ks = 0; ks < 8; ++ks) {
      bf16_8 a = frag16(&sT2[wv * 16 + r16][ks * 32 + quad * 8]);
      bf16_8 b = frag16(wb3 + (size_t)r16 * 256 + ks * 32 + quad * 8);
      acc3 = __builtin_amdgcn_mfma_f32_16x16x32_bf16(a, b, acc3, 0, 0, 0);
    }
    float bb = b3[r16];
#pragma unroll
    for (int r = 0; r < 4; ++r) {
      int row = wv * 16 + quad * 4 + r;
      __builtin_nontemporal_store(acc3[r] + bb, &dmo[(size_t)(e0 + row) * DIN_ + r16]);
    }
  }
}

extern "C" void kernel_launch(void* const* d_in, const int* in_sizes, int n_in,
                              void* d_out, int out_size, void* d_ws, size_t ws_size,
                              hipStream_t stream) {
  const float* input = (const float*)d_in[0];
  const int*   adj   = (const int*)d_in[1];
  const float* h0    = (const float*)d_in[2];
  const void*  lamda = d_in[3];
  const float* alpha = (const float*)d_in[4];
  const void*  lll   = d_in[5];
  const float* dmap  = (const float*)d_in[6];
  const float* nrm   = (const float*)d_in[7];
  const float* Wl    = (const float*)d_in[8];
  const float* Wg    = (const float*)d_in[9];
  const float* lin_w = (const float*)d_in[10];
  const float* lin_b = (const float*)d_in[11];
  const float* w1    = (const float*)d_in[12];
  const float* b1    = (const float*)d_in[13];
  const float* w2    = (const float*)d_in[14];
  const float* b2    = (const float*)d_in[15];
  const float* w3    = (const float*)d_in[16];
  const float* b3    = (const float*)d_in[17];
  const float* ipw   = (const float*)d_in[18];
  const float* ipb   = (const float*)d_in[19];
  const float* opw   = (const float*)d_in[20];
  const float* opb   = (const float*)d_in[21];
  float* out = (float*)d_out;
  float* dmo = out + (size_t)N_ * D_;

  // ---- workspace layout ----
  float* ws   = (float*)d_ws;
  float* xout = ws;                               // N*D f32
  float* qkv  = xout + (size_t)N_ * D_;           // N*3D f32
  float* atto = qkv  + (size_t)N_ * 3 * D_;       // N*D f32
  float* hgl  = atto + (size_t)N_ * D_;           // N*D f32
  unsigned short* wb1 = (unsigned short*)(hgl + (size_t)N_ * D_);  // 512*768
  unsigned short* wb2 = wb1 + 512 * 768;          // 256*512
  unsigned short* wb3 = wb2 + 256 * 512;          // 16*256
  unsigned short* Qb  = wb3 + 16 * 256;           // 2*N*128
  unsigned short* Kb  = Qb + 2 * N_ * HD_;        // 2*N*128
  unsigned short* Vt  = Kb + 2 * N_ * HD_;        // 2*128*N
  unsigned short* t1b = Vt + 2 * HD_ * N_;        // E*512  (fast path only)
  unsigned short* t2b = t1b + (size_t)E_ * 512;   // E*256  (eab)
  unsigned short* eab = t2b;                      // E*256
  int* cnt  = (int*)(t2b + (size_t)E_ * 256);     // 4096
  int* off  = cnt + 4096;                         // 4097
  int* cur  = off + 4100;                         // 4096
  int* perm = cur + 4096;                         // E
  unsigned short* xbp = (unsigned short*)(perm + E_);  // N*D bf16
  unsigned short* lwb = xbp + (size_t)N_ * D_;    // 256*16 bf16 lin_w
  unsigned short* inb = lwb + 256 * DIN_;         // N*D bf16 input
  unsigned short* h0b = inb + (size_t)N_ * D_;    // N*D bf16 h0
  unsigned short* hgb = h0b + (size_t)N_ * D_;    // N*D bf16 h_global
  unsigned short* wqb = hgb + (size_t)N_ * D_;    // 768*256 bf16 in_proj
  unsigned short* wlT = wqb + 768 * 256;          // 256*512 bf16 Wl^T
  unsigned short* wgT = wlT + 256 * 512;          // 256*512 bf16 Wg^T
  unsigned short* opwb = wgT + 256 * 512;         // 256*256 bf16 out_proj
  unsigned short* attob = (unsigned short*)qkv;   // N*D bf16 (qkv region reused post-split)
  const size_t fast_need = (size_t)((char*)(opwb + 256 * 256) - (char*)d_ws);
  const bool fast = ws_size >= fast_need;

  // bf16 weight conversion (native [out,in] layout == MFMA B-frag layout)
  k_f2b<<<dim3((512 * 768 + 255) / 256), 256, 0, stream>>>(w1, wb1, 512 * 768);
  k_f2b<<<dim3((256 * 512 + 255) / 256), 256, 0, stream>>>(w2, wb2, 256 * 512);
  k_f2b<<<dim3((16 * 256 + 255) / 256), 256, 0, stream>>>(w3, wb3, 16 * 256);

  if (fast) {
    // weight/input preps for MFMA qkv + out_proj + final
    k_f2b<<<dim3(N_ * D_ / 256), 256, 0, stream>>>(input, inb, N_ * D_);
    k_f2b<<<dim3(N_ * D_ / 256), 256, 0, stream>>>(h0, h0b, N_ * D_);
    k_f2b<<<dim3((768 * 256 + 255) / 256), 256, 0, stream>>>(ipw, wqb, 768 * 256);
    k_f2b<<<dim3((256 * 256 + 255) / 256), 256, 0, stream>>>(opw, opwb, 256 * 256);
    k_tb<<<dim3((512 * 256 + 255) / 256), 256, 0, stream>>>(Wl, wlT, 512, 256);
    k_tb<<<dim3((512 * 256 + 255) / 256), 256, 0, stream>>>(Wg, wgT, 512, 256);

    // edge_attr via MFMA, CSR build, gather aggregation
    k_f2b<<<dim3((256 * DIN_ + 255) / 256), 256, 0, stream>>>(lin_w, lwb, 256 * DIN_);
    k_edge_attr_mfma<<<dim3(E_ / 64), 256, 0, stream>>>(dmap, lwb, lin_b, eab);
    k_zero<<<dim3(16), 256, 0, stream>>>(cnt, 4096);
    k_hist<<<dim3(E_ / 256), 256, 0, stream>>>(adj, cnt);
    k_scan<<<dim3(1), 1024, 0, stream>>>(cnt, off, cur);
    k_bucket<<<dim3(E_ / 256), 256, 0, stream>>>(adj, cur, perm);
    k_gather<<<dim3(N_), 256, 0, stream>>>(input, adj, eab, nrm, off, perm, xout);
    k_f2b<<<dim3(N_ * D_ / 256), 256, 0, stream>>>(xout, xbp, N_ * D_);

    // MHA: MFMA qkv -> split -> MFMA flash attn (dual out) -> MFMA out_proj
    k_qkv_mfma<<<dim3(192), 256, 0, stream>>>(inb, wqb, ipb, qkv);
    k_qk2b<<<dim3(N_ * 512 / 8 / 256), 256, 0, stream>>>(qkv, Qb, Kb);
    k_v2t<<<dim3(N_ / 64, 2), 256, 0, stream>>>(qkv, Vt);
    k_attn_mfma<<<dim3(N_ / 16, 2), 256, 0, stream>>>(Qb, Kb, Vt, atto, attob);
    k_outproj_mfma<<<dim3(64), 256, 0, stream>>>(attob, opwb, opb, hgl, hgb);

    // output[N,D] via MFMA
    k_final_mfma<<<dim3(64), 256, 0, stream>>>(xbp, h0b, hgb, wlT, wgT,
                                               xout, hgl, h0, alpha, lamda, lll, out);

    // dm_out[E,16]
    k_mlp_gemm1<<<dim3(4096), 256, 0, stream>>>(xbp, adj, eab, wb1, b1, t1b);
    k_mlp_gemm23<<<dim3(E_ / 64), 256, 0, stream>>>(t1b, wb2, b2, wb3, b3, dmo);
  } else {
    k_copy4<<<dim3(N_ * D_ / 4 / 256), 256, 0, stream>>>((const float4*)input, (float4*)xout,
                                                         N_ * D_ / 4);
    k_scatter<<<dim3(E_ / 4), 256, 0, stream>>>(input, adj, dmap, nrm, lin_w, lin_b, xout);
    k_gemm_bt<<<dim3(D3_ / 64, N_ / 64), 256, 0, stream>>>(input, ipw, ipb, qkv, N_, D3_, D_);
    k_qk2b<<<dim3(N_ * 512 / 8 / 256), 256, 0, stream>>>(qkv, Qb, Kb);
    k_v2t<<<dim3(N_ / 64, 2), 256, 0, stream>>>(qkv, Vt);
    k_attn_mfma<<<dim3(N_ / 16, 2), 256, 0, stream>>>(Qb, Kb, Vt, atto, (unsigned short*)qkv);
    k_gemm_bt<<<dim3(D_ / 64, N_ / 64), 256, 0, stream>>>(atto, opw, opb, hgl, N_, D_, D_);
    k_final<<<dim3(4, N_ / 64), 256, 0, stream>>>(xout, hgl, h0, Wl, Wg, alpha, lamda, lll, out);
    k_edge_mlp_mfma<<<dim3(E_ / 32), 256, 0, stream>>>(xout, adj, dmap, lin_w, lin_b,
                                                       wb1, b1, wb2, b2, wb3, b3, dmo);
  }
}

// Round 17
// 712.178 us; speedup vs baseline: 1.0387x; 1.0387x over previous
//
#include <hip/hip_runtime.h>
#include <hip/hip_bf16.h>
#include <math.h>

// Problem constants
constexpr int N_   = 4096;
constexpr int E_   = 131072;
constexpr int D_   = 256;
constexpr int DIN_ = 16;
constexpr int D3_  = 768;   // 3*D
constexpr int HD_  = 128;   // head dim

typedef __bf16 bf16_8 __attribute__((ext_vector_type(8)));
typedef float  f32x4  __attribute__((ext_vector_type(4)));
typedef float  f32x4v __attribute__((ext_vector_type(4)));
typedef unsigned int u32x4 __attribute__((ext_vector_type(4)));   // NT-store-compatible 16B

// ---- bf16 helpers ----
__device__ __forceinline__ unsigned short f2b(float f) {
  unsigned int u = __float_as_uint(f);
  u = u + 0x7fffu + ((u >> 16) & 1u);   // round-to-nearest-even
  return (unsigned short)(u >> 16);
}
__device__ __forceinline__ float b2f(unsigned short s) {
  return __uint_as_float(((unsigned int)s) << 16);
}
__device__ __forceinline__ unsigned int pack2(unsigned short lo, unsigned short hi) {
  return (unsigned int)lo | ((unsigned int)hi << 16);
}
__device__ __forceinline__ bf16_8 frag16(const unsigned short* p) {
  uint4 v = *(const uint4*)p;           // 16B load (LDS b128 or global dwordx4)
  return __builtin_bit_cast(bf16_8, v);
}
__device__ __forceinline__ float4 ntload4(const void* p) {
  f32x4v v = __builtin_nontemporal_load((const f32x4v*)p);
  float4 r;
  r.x = v[0]; r.y = v[1]; r.z = v[2]; r.w = v[3];
  return r;
}
__device__ __forceinline__ void ntstore16(void* dst, uint4 v) {
  __builtin_nontemporal_store(__builtin_bit_cast(u32x4, v), (u32x4*)dst);
}
// async global->LDS, 16B per lane; LDS dst = uniform base + lane*16
__device__ __forceinline__ void gl2lds16(const unsigned short* g, unsigned short* l) {
  __builtin_amdgcn_global_load_lds(
      (const __attribute__((address_space(1))) void*)g,
      (__attribute__((address_space(3))) void*)l, 16, 0, 0);
}

// Python scalar may arrive as int32 or float32 bits; values here are small ints.
__device__ __forceinline__ float scalar_as_float(const void* p) {
  int iv = *(const int*)p;
  if (iv >= 1 && iv <= 1000000) return (float)iv;  // plausible int
  return __int_as_float(iv);                       // else float bits
}

__device__ __forceinline__ float gelu_exact(float v) {
  return 0.5f * v * (1.0f + erff(v * 0.70710678118654752f));
}

// ---------------- f32 -> bf16 convert ----------------
__global__ void k_f2b(const float* __restrict__ src, unsigned short* __restrict__ dst, int n) {
  int i = blockIdx.x * 256 + threadIdx.x;
  if (i < n) dst[i] = f2b(src[i]);
}

// ---------------- transpose + f2b: src[K,J] fp32 -> dst[J,K] bf16 ----------------
__global__ void k_tb(const float* __restrict__ src, unsigned short* __restrict__ dst,
                     int K, int J) {
  int idx = blockIdx.x * 256 + threadIdx.x;
  if (idx < K * J) {
    int k = idx % K, j = idx / K;
    dst[idx] = f2b(src[(size_t)k * J + j]);
  }
}

// ---------------- copy (float4) ----------------
__global__ void k_copy4(const float4* __restrict__ src, float4* __restrict__ dst, int n4) {
  int idx = blockIdx.x * 256 + threadIdx.x;
  if (idx < n4) dst[idx] = src[idx];
}

// ---------------- edge_attr via zero-padded MFMA ----------------
__global__ __launch_bounds__(256) void k_edge_attr_mfma(
    const float* __restrict__ dmap, const unsigned short* __restrict__ lwb,
    const float* __restrict__ lin_b, unsigned short* __restrict__ eab) {
  __shared__ unsigned short sT[4][16][264];   // per-wave C tile (bounce), 33 KB
  const int tid  = threadIdx.x;
  const int lane = tid & 63, wv = tid >> 6;
  const int r16  = lane & 15, quad = lane >> 4;
  const int e0   = blockIdx.x * 64 + wv * 16;

  const uint4 z4 = make_uint4(0u, 0u, 0u, 0u);
  bf16_8 bfr[16];
#pragma unroll
  for (int n = 0; n < 16; ++n) {
    uint4 v = z4;
    if (quad < 2) v = *(const uint4*)(lwb + (size_t)(n * 16 + r16) * DIN_ + quad * 8);
    bfr[n] = __builtin_bit_cast(bf16_8, v);
  }
  bf16_8 af;
  {
    uint4 p = z4;
    if (quad < 2) {
      const float4* dp = (const float4*)(dmap + (size_t)(e0 + r16) * DIN_ + quad * 8);
      float4 a = dp[0], b = dp[1];
      p = make_uint4(pack2(f2b(a.x), f2b(a.y)), pack2(f2b(a.z), f2b(a.w)),
                     pack2(f2b(b.x), f2b(b.y)), pack2(f2b(b.z), f2b(b.w)));
    }
    af = __builtin_bit_cast(bf16_8, p);
  }

  const f32x4 zz = {0.f, 0.f, 0.f, 0.f};
  f32x4 acc[16];
#pragma unroll
  for (int n = 0; n < 16; ++n) acc[n] = zz;
#pragma unroll
  for (int n = 0; n < 16; ++n)
    acc[n] = __builtin_amdgcn_mfma_f32_16x16x32_bf16(af, bfr[n], acc[n], 0, 0, 0);

#pragma unroll
  for (int n = 0; n < 16; ++n) {
    float bb = lin_b[n * 16 + r16];
#pragma unroll
    for (int rg = 0; rg < 4; ++rg)
      sT[wv][quad * 4 + rg][n * 16 + r16] = f2b(acc[n][rg] + bb);
  }
#pragma unroll
  for (int it = 0; it < 8; ++it) {
    int flat = it * 64 + lane;
    int row = flat >> 5, g = flat & 31;
    uint4 v = *(const uint4*)&sT[wv][row][g * 8];
    ntstore16(&eab[(size_t)(e0 + row) * D_ + g * 8], v);
  }
}

// ================= CSR build (per-launch) + gather aggregation =================
__global__ void k_zero(int* __restrict__ p, int n) {
  int i = blockIdx.x * 256 + threadIdx.x;
  if (i < n) p[i] = 0;
}
__global__ void k_hist(const int* __restrict__ adj, int* __restrict__ cnt) {
  int e = blockIdx.x * 256 + threadIdx.x;
  atomicAdd(&cnt[adj[E_ + e]], 1);
}
__global__ __launch_bounds__(1024) void k_scan(const int* __restrict__ cnt,
                                               int* __restrict__ off, int* __restrict__ cur) {
  __shared__ int ps[1024];
  int tid = threadIdx.x;
  int base = tid * 4;
  int a0 = cnt[base], a1 = cnt[base + 1], a2 = cnt[base + 2], a3 = cnt[base + 3];
  int tsum = a0 + a1 + a2 + a3;
  ps[tid] = tsum;
  __syncthreads();
  for (int st = 1; st < 1024; st <<= 1) {
    int v = (tid >= st) ? ps[tid - st] : 0;
    __syncthreads();
    ps[tid] += v;
    __syncthreads();
  }
  int excl = ps[tid] - tsum;
  int o0 = excl, o1 = excl + a0, o2 = o1 + a1, o3 = o2 + a2;
  off[base] = o0; off[base + 1] = o1; off[base + 2] = o2; off[base + 3] = o3;
  cur[base] = o0; cur[base + 1] = o1; cur[base + 2] = o2; cur[base + 3] = o3;
  if (tid == 1023) off[4096] = o3 + a3;
}
__global__ void k_bucket(const int* __restrict__ adj, int* __restrict__ cur,
                         int* __restrict__ perm) {
  int e = blockIdx.x * 256 + threadIdx.x;
  int p = atomicAdd(&cur[adj[E_ + e]], 1);
  perm[p] = e;
}
__global__ __launch_bounds__(256) void k_gather(
    const float* __restrict__ x, const int* __restrict__ adj,
    const unsigned short* __restrict__ eab, const float* __restrict__ nrm,
    const int* __restrict__ off, const int* __restrict__ perm,
    float* __restrict__ xout) {
  int n = blockIdx.x, t = threadIdx.x;
  int beg = off[n], end = off[n + 1];
  float acc = x[(size_t)n * D_ + t];
  int i = beg;
  for (; i + 1 < end; i += 2) {
    int e0 = perm[i], e1 = perm[i + 1];
    int s0 = adj[e0], s1 = adj[e1];
    float w0 = nrm[e0], w1 = nrm[e1];
    float xa = x[(size_t)s0 * D_ + t];
    float xb = x[(size_t)s1 * D_ + t];
    float ea0 = b2f(eab[(size_t)e0 * D_ + t]);
    float ea1 = b2f(eab[(size_t)e1 * D_ + t]);
    acc += w0 * (xa + ea0) + w1 * (xb + ea1);
  }
  if (i < end) {
    int e0 = perm[i];
    int s0 = adj[e0];
    float w0 = nrm[e0];
    acc += w0 * (x[(size_t)s0 * D_ + t] + b2f(eab[(size_t)e0 * D_ + t]));
  }
  xout[(size_t)n * D_ + t] = acc;
}

// ---------------- legacy scatter (fallback path) ----------------
__global__ __launch_bounds__(256) void k_scatter(
    const float* __restrict__ x, const int* __restrict__ adj,
    const float* __restrict__ dmap, const float* __restrict__ nrm,
    const float* __restrict__ lin_w, const float* __restrict__ lin_b,
    float* __restrict__ xout) {
  __shared__ float s_dm[4][DIN_];
  int te = threadIdx.x >> 6;
  int d4 = threadIdx.x & 63;
  int e  = blockIdx.x * 4 + te;
  if (d4 < DIN_) s_dm[te][d4] = dmap[(size_t)e * DIN_ + d4];
  __syncthreads();
  int vs = adj[e];
  int vd = adj[E_ + e];
  float w = nrm[e];
  int d = d4 * 4;
  float4 xs = *(const float4*)(x + (size_t)vs * D_ + d);
  float ea[4];
#pragma unroll
  for (int q = 0; q < 4; q++) {
    const float* lw = lin_w + (size_t)(d + q) * DIN_;
    float acc = lin_b[d + q];
#pragma unroll
    for (int k = 0; k < DIN_; k++) acc += s_dm[te][k] * lw[k];
    ea[q] = acc;
  }
  float* op = xout + (size_t)vd * D_ + d;
  atomicAdd(op + 0, w * (xs.x + ea[0]));
  atomicAdd(op + 1, w * (xs.y + ea[1]));
  atomicAdd(op + 2, w * (xs.z + ea[2]));
  atomicAdd(op + 3, w * (xs.w + ea[3]));
}

// ---------------- C[M,N] = A[M,K] @ B[N,K]^T + bias (fp32, fallback) ----------------
__global__ __launch_bounds__(256) void k_gemm_bt(
    const float* __restrict__ A, const float* __restrict__ B,
    const float* __restrict__ bias, float* __restrict__ C,
    int M, int Nn, int K) {
  __shared__ float sA[16][68];
  __shared__ float sB[16][68];
  int bm = blockIdx.y * 64, bn = blockIdx.x * 64;
  int tid = threadIdx.x;
  int tr = tid >> 4, tc = tid & 15;
  float acc[4][4] = {};
  for (int k0 = 0; k0 < K; k0 += 16) {
    for (int i = tid; i < 1024; i += 256) {
      int r = i >> 4, c = i & 15;
      sA[c][r] = A[(size_t)(bm + r) * K + k0 + c];
      sB[c][r] = B[(size_t)(bn + r) * K + k0 + c];
    }
    __syncthreads();
#pragma unroll
    for (int kk = 0; kk < 16; kk++) {
      float av[4], bv[4];
#pragma unroll
      for (int i = 0; i < 4; i++) av[i] = sA[kk][tr * 4 + i];
#pragma unroll
      for (int j = 0; j < 4; j++) bv[j] = sB[kk][tc * 4 + j];
#pragma unroll
      for (int i = 0; i < 4; i++)
#pragma unroll
        for (int j = 0; j < 4; j++) acc[i][j] += av[i] * bv[j];
    }
    __syncthreads();
  }
#pragma unroll
  for (int i = 0; i < 4; i++) {
    int r = bm + tr * 4 + i;
#pragma unroll
    for (int j = 0; j < 4; j++) {
      int c = bn + tc * 4 + j;
      C[(size_t)r * Nn + c] = acc[i][j] + bias[c];
    }
  }
}

// ---------------- qkv proj via MFMA: bf16 in, fp32 qkv out ----------------
__global__ __launch_bounds__(256) void k_qkv_mfma(
    const unsigned short* __restrict__ inb, const unsigned short* __restrict__ wqb,
    const float* __restrict__ ipb, float* __restrict__ qkv) {
  __shared__ unsigned short sA[128][72];
  __shared__ unsigned short sB[128][72];
  const int b   = blockIdx.x;
  const int j0  = (b % 6) * 128;
  const int m0  = (b / 6) * 128;
  const int tid = threadIdx.x;
  const int lane = tid & 63, wv = tid >> 6;
  const int r16  = lane & 15, quad = lane >> 4;
  const int sr   = tid >> 1, sh = (tid & 1) * 32;

  const unsigned short* ra = inb + (size_t)(m0 + sr) * D_;
  const unsigned short* rb = wqb + (size_t)(j0 + sr) * D_;

  const f32x4 zz = {0.f, 0.f, 0.f, 0.f};
  f32x4 acc[2][8];
#pragma unroll
  for (int m = 0; m < 2; ++m)
#pragma unroll
    for (int n = 0; n < 8; ++n) acc[m][n] = zz;

  for (int ki = 0; ki < 4; ++ki) {
    __syncthreads();
    {
      const uint4* s    = (const uint4*)(ra + ki * 64 + sh);
      const uint4* bsrc = (const uint4*)(rb + ki * 64 + sh);
      uint4* da = (uint4*)&sA[sr][sh];
      uint4* db = (uint4*)&sB[sr][sh];
#pragma unroll
      for (int i = 0; i < 4; ++i) { da[i] = s[i]; db[i] = bsrc[i]; }
    }
    __syncthreads();
#pragma unroll
    for (int kk = 0; kk < 2; ++kk) {
      bf16_8 a0 = frag16(&sA[wv * 32 + r16][kk * 32 + quad * 8]);
      bf16_8 a1 = frag16(&sA[wv * 32 + 16 + r16][kk * 32 + quad * 8]);
#pragma unroll
      for (int n = 0; n < 8; ++n) {
        bf16_8 bf = frag16(&sB[n * 16 + r16][kk * 32 + quad * 8]);
        acc[0][n] = __builtin_amdgcn_mfma_f32_16x16x32_bf16(a0, bf, acc[0][n], 0, 0, 0);
        acc[1][n] = __builtin_amdgcn_mfma_f32_16x16x32_bf16(a1, bf, acc[1][n], 0, 0, 0);
      }
    }
  }
#pragma unroll
  for (int m = 0; m < 2; ++m)
#pragma unroll
    for (int n = 0; n < 8; ++n) {
      int col = j0 + n * 16 + r16;
      float bb = ipb[col];
#pragma unroll
      for (int rg = 0; rg < 4; ++rg) {
        int row = m0 + wv * 32 + m * 16 + quad * 4 + rg;
        qkv[(size_t)row * D3_ + col] = acc[m][n][rg] + bb;
      }
    }
}

// ---------------- out_proj via MFMA: hgl = attob @ opwb^T + opb; hgb = bf16 ----
__global__ __launch_bounds__(256) void k_outproj_mfma(
    const unsigned short* __restrict__ attob, const unsigned short* __restrict__ opwb,
    const float* __restrict__ opb, float* __restrict__ hgl,
    unsigned short* __restrict__ hgb) {
  __shared__ unsigned short sA[128][72];
  __shared__ unsigned short sB[128][72];
  const int b   = blockIdx.x;
  const int j0  = (b & 1) * 128;
  const int m0  = (b >> 1) * 128;
  const int tid = threadIdx.x;
  const int lane = tid & 63, wv = tid >> 6;
  const int r16  = lane & 15, quad = lane >> 4;
  const int sr   = tid >> 1, sh = (tid & 1) * 32;

  const unsigned short* ra = attob + (size_t)(m0 + sr) * D_;
  const unsigned short* rb = opwb + (size_t)(j0 + sr) * D_;

  const f32x4 zz = {0.f, 0.f, 0.f, 0.f};
  f32x4 acc[2][8];
#pragma unroll
  for (int m = 0; m < 2; ++m)
#pragma unroll
    for (int n = 0; n < 8; ++n) acc[m][n] = zz;

  for (int ki = 0; ki < 4; ++ki) {
    __syncthreads();
    {
      const uint4* s    = (const uint4*)(ra + ki * 64 + sh);
      const uint4* bsrc = (const uint4*)(rb + ki * 64 + sh);
      uint4* da = (uint4*)&sA[sr][sh];
      uint4* db = (uint4*)&sB[sr][sh];
#pragma unroll
      for (int i = 0; i < 4; ++i) { da[i] = s[i]; db[i] = bsrc[i]; }
    }
    __syncthreads();
#pragma unroll
    for (int kk = 0; kk < 2; ++kk) {
      bf16_8 a0 = frag16(&sA[wv * 32 + r16][kk * 32 + quad * 8]);
      bf16_8 a1 = frag16(&sA[wv * 32 + 16 + r16][kk * 32 + quad * 8]);
#pragma unroll
      for (int n = 0; n < 8; ++n) {
        bf16_8 bf = frag16(&sB[n * 16 + r16][kk * 32 + quad * 8]);
        acc[0][n] = __builtin_amdgcn_mfma_f32_16x16x32_bf16(a0, bf, acc[0][n], 0, 0, 0);
        acc[1][n] = __builtin_amdgcn_mfma_f32_16x16x32_bf16(a1, bf, acc[1][n], 0, 0, 0);
      }
    }
  }
#pragma unroll
  for (int m = 0; m < 2; ++m)
#pragma unroll
    for (int n = 0; n < 8; ++n) {
      int col = j0 + n * 16 + r16;
      float bb = opb[col];
#pragma unroll
      for (int rg = 0; rg < 4; ++rg) {
        int row = m0 + wv * 32 + m * 16 + quad * 4 + rg;
        float v = acc[m][n][rg] + bb;
        size_t idx = (size_t)row * D_ + col;
        hgl[idx] = v;
        hgb[idx] = f2b(v);
      }
    }
}

// ---------------- final combine via MFMA ----------------
__global__ __launch_bounds__(256) void k_final_mfma(
    const unsigned short* __restrict__ xbp, const unsigned short* __restrict__ h0b,
    const unsigned short* __restrict__ hgb,
    const unsigned short* __restrict__ wlT, const unsigned short* __restrict__ wgT,
    const float* __restrict__ hl, const float* __restrict__ hg, const float* __restrict__ h0,
    const float* __restrict__ alpha_p, const void* lamda_p, const void* l_p,
    float* __restrict__ out) {
  __shared__ unsigned short sA[128][72];
  __shared__ unsigned short sB[128][72];
  const int b   = blockIdx.x;
  const int j0  = (b & 1) * 128;
  const int m0  = (b >> 1) * 128;
  const int tid = threadIdx.x;
  const int lane = tid & 63, wv = tid >> 6;
  const int r16  = lane & 15, quad = lane >> 4;
  const int sr   = tid >> 1, sh = (tid & 1) * 32;

  const f32x4 zz = {0.f, 0.f, 0.f, 0.f};
  f32x4 acc[2][8];
#pragma unroll
  for (int m = 0; m < 2; ++m)
#pragma unroll
    for (int n = 0; n < 8; ++n) acc[m][n] = zz;

  const size_t arow = (size_t)(m0 + sr) * D_;
  const size_t brow = (size_t)(j0 + sr) * 512;

  for (int ki = 0; ki < 16; ++ki) {
    __syncthreads();
    {
      const int gc = ki * 64 + sh;
      const unsigned short* ap =
          (gc < 256) ? xbp + arow + gc
        : (gc < 512) ? h0b + arow + (gc - 256)
        : (gc < 768) ? hgb + arow + (gc - 512)
                     : h0b + arow + (gc - 768);
      const unsigned short* bp = (gc < 512) ? wlT + brow + gc : wgT + brow + (gc - 512);
      const uint4* s    = (const uint4*)ap;
      const uint4* bsrc = (const uint4*)bp;
      uint4* da = (uint4*)&sA[sr][sh];
      uint4* db = (uint4*)&sB[sr][sh];
#pragma unroll
      for (int i = 0; i < 4; ++i) { da[i] = s[i]; db[i] = bsrc[i]; }
    }
    __syncthreads();
#pragma unroll
    for (int kk = 0; kk < 2; ++kk) {
      bf16_8 a0 = frag16(&sA[wv * 32 + r16][kk * 32 + quad * 8]);
      bf16_8 a1 = frag16(&sA[wv * 32 + 16 + r16][kk * 32 + quad * 8]);
#pragma unroll
      for (int n = 0; n < 8; ++n) {
        bf16_8 bf = frag16(&sB[n * 16 + r16][kk * 32 + quad * 8]);
        acc[0][n] = __builtin_amdgcn_mfma_f32_16x16x32_bf16(a0, bf, acc[0][n], 0, 0, 0);
        acc[1][n] = __builtin_amdgcn_mfma_f32_16x16x32_bf16(a1, bf, acc[1][n], 0, 0, 0);
      }
    }
  }
  float theta = fminf(1.f, logf(scalar_as_float(lamda_p) / scalar_as_float(l_p) + 1.f));
  float a = alpha_p[0];
  float omt = 1.f - theta;
#pragma unroll
  for (int m = 0; m < 2; ++m)
#pragma unroll
    for (int n = 0; n < 8; ++n) {
      int col = j0 + n * 16 + r16;
#pragma unroll
      for (int rg = 0; rg < 4; ++rg) {
        int row = m0 + wv * 32 + m * 16 + quad * 4 + rg;
        size_t idx = (size_t)row * D_ + col;
        out[idx] = theta * acc[m][n][rg] +
                   omt * ((1.f - a) * (hl[idx] + hg[idx]) + 2.f * a * h0[idx]);
      }
    }
}

// ---------------- qkv split: fp32 [N,768] -> bf16 Qb/Kb [h][n][128] ----------------
__global__ void k_qk2b(const float* __restrict__ qkv,
                       unsigned short* __restrict__ Qb, unsigned short* __restrict__ Kb) {
  int off = (blockIdx.x * 256 + threadIdx.x) * 8;   // over N*512
  int n = off >> 9, c = off & 511;
  const float* src = qkv + (size_t)n * D3_ + c;     // Q cols 0..255, K cols 256..511
  float4 a = *(const float4*)src;
  float4 b = *(const float4*)(src + 4);
  uint4 p = {pack2(f2b(a.x), f2b(a.y)), pack2(f2b(a.z), f2b(a.w)),
             pack2(f2b(b.x), f2b(b.y)), pack2(f2b(b.z), f2b(b.w))};
  int cc = c & 255;
  int hh = cc >> 7, d = cc & 127;
  unsigned short* dst = (c < 256 ? Qb : Kb) + (size_t)hh * N_ * HD_ + (size_t)n * HD_ + d;
  *(uint4*)dst = p;
}

// ---------------- V transpose: fp32 qkv V-cols -> bf16 Vt [h][128][N] ----------------
__global__ __launch_bounds__(256) void k_v2t(const float* __restrict__ qkv,
                                             unsigned short* __restrict__ Vt) {
  __shared__ unsigned short sv[64][136];
  int h = blockIdx.y;
  int n0 = blockIdx.x * 64;
  int tid = threadIdx.x;
#pragma unroll
  for (int it = 0; it < 4; ++it) {
    int off = (tid + it * 256) * 8;
    int r = off >> 7, d = off & 127;
    const float* src = qkv + (size_t)(n0 + r) * D3_ + 2 * D_ + h * HD_ + d;
    float4 a = *(const float4*)src;
    float4 b = *(const float4*)(src + 4);
    uint4 p = {pack2(f2b(a.x), f2b(a.y)), pack2(f2b(a.z), f2b(a.w)),
               pack2(f2b(b.x), f2b(b.y)), pack2(f2b(b.z), f2b(b.w))};
    *(uint4*)&sv[r][d] = p;
  }
  __syncthreads();
#pragma unroll
  for (int it = 0; it < 4; ++it) {
    int off = (tid + it * 256) * 8;
    int d = off >> 6, k = off & 63;
    unsigned short t[8];
#pragma unroll
    for (int j = 0; j < 8; ++j) t[j] = sv[k + j][d];
    uint4 p = {pack2(t[0], t[1]), pack2(t[2], t[3]),
               pack2(t[4], t[5]), pack2(t[6], t[7])};
    *(uint4*)(Vt + (size_t)h * HD_ * N_ + (size_t)d * N_ + n0 + k) = p;
  }
}

// ---------------- MFMA flash attention, H=2, HD=128 (dual fp32+bf16 out) ----------------
__global__ __launch_bounds__(256) void k_attn_mfma(
    const unsigned short* __restrict__ Qb, const unsigned short* __restrict__ Kb,
    const unsigned short* __restrict__ Vt, float* __restrict__ o_out,
    unsigned short* __restrict__ ob) {
  __shared__ unsigned short sK[64][136];   // keys x dims (+8 pad)
  __shared__ unsigned short sV[128][72];   // dims x keys (+8 pad)
  __shared__ float          sS[16][68];    // scores
  __shared__ unsigned short sP[16][72];    // probs bf16 (A-frag layout)
  __shared__ float sm[16], sl[16], sa[16];

  const int tid  = threadIdx.x;
  const int h    = blockIdx.y;
  const int q0   = blockIdx.x * 16;
  const int lane = tid & 63;
  const int wv   = tid >> 6;
  const int r16  = lane & 15;
  const int quad = lane >> 4;

  bf16_8 qf[4];
#pragma unroll
  for (int kk = 0; kk < 4; ++kk)
    qf[kk] = frag16(Qb + (size_t)h * N_ * HD_ + (size_t)(q0 + r16) * HD_ + kk * 32 + quad * 8);

  if (tid < 16) { sm[tid] = -1e30f; sl[tid] = 0.f; }

  const f32x4 zz = {0.f, 0.f, 0.f, 0.f};
  f32x4 o0 = zz, o1 = zz;

  const unsigned short* Kh = Kb + (size_t)h * N_ * HD_;
  const unsigned short* Vh = Vt + (size_t)h * HD_ * N_;

  for (int c0 = 0; c0 < N_; c0 += 64) {
    __syncthreads();
#pragma unroll
    for (int it = 0; it < 4; ++it) {
      int off = (tid + it * 256) * 8;
      int key = off >> 7, d = off & 127;
      *(uint4*)&sK[key][d] = *(const uint4*)(Kh + (size_t)(c0 + key) * HD_ + d);
    }
#pragma unroll
    for (int it = 0; it < 4; ++it) {
      int off = (tid + it * 256) * 8;
      int d = off >> 6, k = off & 63;
      *(uint4*)&sV[d][k] = *(const uint4*)(Vh + (size_t)d * N_ + c0 + k);
    }
    __syncthreads();
    f32x4 s = zz;
#pragma unroll
    for (int kk = 0; kk < 4; ++kk) {
      bf16_8 bf = frag16(&sK[wv * 16 + r16][kk * 32 + quad * 8]);
      s = __builtin_amdgcn_mfma_f32_16x16x32_bf16(qf[kk], bf, s, 0, 0, 0);
    }
    const float sc = 0.08838834764831845f;   // 1/sqrt(128)
#pragma unroll
    for (int r = 0; r < 4; ++r)
      sS[quad * 4 + r][wv * 16 + r16] = s[r] * sc;
    __syncthreads();
    {
      int row = tid >> 4, i = tid & 15;
      float4 v = *(const float4*)&sS[row][i * 4];
      float mx = fmaxf(fmaxf(v.x, v.y), fmaxf(v.z, v.w));
#pragma unroll
      for (int m = 1; m <= 8; m <<= 1) mx = fmaxf(mx, __shfl_xor(mx, m));
      float mo = sm[row];
      float mn = fmaxf(mo, mx);
      float p0 = __expf(v.x - mn), p1 = __expf(v.y - mn);
      float p2 = __expf(v.z - mn), p3 = __expf(v.w - mn);
      float ps = p0 + p1 + p2 + p3;
#pragma unroll
      for (int m = 1; m <= 8; m <<= 1) ps += __shfl_xor(ps, m);
      uint2 pk = {pack2(f2b(p0), f2b(p1)), pack2(f2b(p2), f2b(p3))};
      *(uint2*)&sP[row][i * 4] = pk;
      if (i == 0) {
        float al = __expf(mo - mn);
        sl[row] = sl[row] * al + ps;
        sm[row] = mn;
        sa[row] = al;
      }
    }
    __syncthreads();
    {
      float al0 = sa[quad * 4 + 0], al1 = sa[quad * 4 + 1];
      float al2 = sa[quad * 4 + 2], al3 = sa[quad * 4 + 3];
      o0[0] *= al0; o0[1] *= al1; o0[2] *= al2; o0[3] *= al3;
      o1[0] *= al0; o1[1] *= al1; o1[2] *= al2; o1[3] *= al3;
#pragma unroll
      for (int kk = 0; kk < 2; ++kk) {
        bf16_8 pa = frag16(&sP[r16][kk * 32 + quad * 8]);
        bf16_8 v0 = frag16(&sV[wv * 32 + r16][kk * 32 + quad * 8]);
        bf16_8 v1 = frag16(&sV[wv * 32 + 16 + r16][kk * 32 + quad * 8]);
        o0 = __builtin_amdgcn_mfma_f32_16x16x32_bf16(pa, v0, o0, 0, 0, 0);
        o1 = __builtin_amdgcn_mfma_f32_16x16x32_bf16(pa, v1, o1, 0, 0, 0);
      }
    }
  }
  {
    float i0 = 1.f / sl[quad * 4 + 0], i1 = 1.f / sl[quad * 4 + 1];
    float i2 = 1.f / sl[quad * 4 + 2], i3 = 1.f / sl[quad * 4 + 3];
    float vv[8];
    vv[0] = o0[0] * i0; vv[1] = o0[1] * i1; vv[2] = o0[2] * i2; vv[3] = o0[3] * i3;
    vv[4] = o1[0] * i0; vv[5] = o1[1] * i1; vv[6] = o1[2] * i2; vv[7] = o1[3] * i3;
#pragma unroll
    for (int g = 0; g < 2; ++g)
#pragma unroll
      for (int rg = 0; rg < 4; ++rg) {
        size_t idx = (size_t)(q0 + quad * 4 + rg) * D_ + h * HD_ + wv * 32 + g * 16 + r16;
        float v = vv[g * 4 + rg];
        o_out[idx] = v;
        ob[idx] = f2b(v);
      }
  }
}

// ---------------- final combine (fp32, fallback) ----------------
__global__ __launch_bounds__(256) void k_final(
    const float* __restrict__ hl, const float* __restrict__ hg, const float* __restrict__ h0,
    const float* __restrict__ Wl, const float* __restrict__ Wg,
    const float* __restrict__ alpha_p, const void* lamda_p, const void* l_p,
    float* __restrict__ out) {
  __shared__ float sA[16][68];
  __shared__ float sB[16][68];
  float theta = fminf(1.f, logf(scalar_as_float(lamda_p) / scalar_as_float(l_p) + 1.f));
  float a = alpha_p[0];
  int bm = blockIdx.y * 64, bn = blockIdx.x * 64;
  int tid = threadIdx.x, tr = tid >> 4, tc = tid & 15;
  float acc[4][4] = {};
  for (int k0 = 0; k0 < 1024; k0 += 16) {
    for (int i = tid; i < 1024; i += 256) {
      int r = i >> 4, c = i & 15;
      int k = k0 + c;
      const float* src = (k < 256) ? hl : (k < 512) ? h0 : (k < 768) ? hg : h0;
      sA[c][r] = src[(size_t)(bm + r) * 256 + (k & 255)];
    }
    for (int i = tid; i < 1024; i += 256) {
      int kk = i >> 6, j = i & 63;
      int k = k0 + kk;
      const float* Bp = (k < 512) ? (Wl + (size_t)k * 256) : (Wg + (size_t)(k - 512) * 256);
      sB[kk][j] = Bp[bn + j];
    }
    __syncthreads();
#pragma unroll
    for (int kk = 0; kk < 16; kk++) {
      float av[4], bv[4];
#pragma unroll
      for (int i = 0; i < 4; i++) av[i] = sA[kk][tr * 4 + i];
#pragma unroll
      for (int j = 0; j < 4; j++) bv[j] = sB[kk][tc * 4 + j];
#pragma unroll
      for (int i = 0; i < 4; i++)
#pragma unroll
        for (int j = 0; j < 4; j++) acc[i][j] += av[i] * bv[j];
    }
    __syncthreads();
  }
  float omt = 1.f - theta;
#pragma unroll
  for (int i = 0; i < 4; i++) {
    int r = bm + tr * 4 + i;
#pragma unroll
    for (int j = 0; j < 4; j++) {
      int c = bn + tc * 4 + j;
      size_t idx = (size_t)r * 256 + c;
      out[idx] = theta * acc[i][j] + omt * ((1.f - a) * (hl[idx] + hg[idx]) + 2.f * a * h0[idx]);
    }
  }
}

// ================= edge MLP as tiled GEMMs (fast path) =================
// GEMM1: h3[E,768] @ wb1^T -> gelu -> t1[E,512] bf16. 128x128 tile, BK=64.
__global__ __launch_bounds__(256) void k_mlp_gemm1(
    const unsigned short* __restrict__ xb, const int* __restrict__ adj,
    const unsigned short* __restrict__ eab, const unsigned short* __restrict__ wb1,
    const float* __restrict__ b1, unsigned short* __restrict__ t1) {
  __shared__ unsigned short lA[16 * 512];   // 16 A-frags x 1KB
  __shared__ unsigned short lB[16 * 512];   // 16 B-frags x 1KB
  const int b    = blockIdx.x;
  const int j0   = ((b >> 3) & 3) * 128;
  const int e0   = (((b >> 5) << 3) | (b & 7)) * 128;
  const int tid  = threadIdx.x;
  const int lane = tid & 63, wv = tid >> 6;
  const int r16  = lane & 15, quad = lane >> 4;

  const int row0 = e0 + wv * 32 + r16;
  const int row1 = row0 + 16;
  const int vs0 = adj[row0], vs1 = adj[row1];
  const int vd0 = adj[E_ + row0], vd1 = adj[E_ + row1];
  const unsigned short* pb0 = wb1 + (size_t)(j0 + (wv * 2 + 0) * 16 + r16) * 768 + quad * 8;
  const unsigned short* pb1 = wb1 + (size_t)(j0 + (wv * 2 + 1) * 16 + r16) * 768 + quad * 8;

  const f32x4 zz = {0.f, 0.f, 0.f, 0.f};
  f32x4 acc[2][8];
#pragma unroll
  for (int m = 0; m < 2; ++m)
#pragma unroll
    for (int n = 0; n < 8; ++n) acc[m][n] = zz;

  for (int ki = 0; ki < 12; ++ki) {
    __syncthreads();
    {
      const int seg = ki >> 2;
      const int col = (ki & 3) * 64 + quad * 8;
      const unsigned short* ap0;
      const unsigned short* ap1;
      if (seg == 1) {
        ap0 = eab + (size_t)row0 * D_;
        ap1 = eab + (size_t)row1 * D_;
      } else {
        int n0 = (seg == 0) ? vs0 : vd0;
        int n1 = (seg == 0) ? vs1 : vd1;
        ap0 = xb + (size_t)n0 * D_;
        ap1 = xb + (size_t)n1 * D_;
      }
#pragma unroll
      for (int kk = 0; kk < 2; ++kk) {
        gl2lds16(ap0 + col + kk * 32, &lA[(wv * 4 + kk) * 512]);
        gl2lds16(ap1 + col + kk * 32, &lA[(wv * 4 + 2 + kk) * 512]);
        gl2lds16(pb0 + ki * 64 + kk * 32, &lB[((wv * 2 + 0) * 2 + kk) * 512]);
        gl2lds16(pb1 + ki * 64 + kk * 32, &lB[((wv * 2 + 1) * 2 + kk) * 512]);
      }
    }
    __builtin_amdgcn_s_waitcnt(0);
    __syncthreads();
#pragma unroll
    for (int kk = 0; kk < 2; ++kk) {
      bf16_8 a0 = frag16(&lA[(wv * 4 + kk) * 512 + lane * 8]);
      bf16_8 a1 = frag16(&lA[(wv * 4 + 2 + kk) * 512 + lane * 8]);
#pragma unroll
      for (int n = 0; n < 8; ++n) {
        bf16_8 bf = frag16(&lB[(n * 2 + kk) * 512 + lane * 8]);
        acc[0][n] = __builtin_amdgcn_mfma_f32_16x16x32_bf16(a0, bf, acc[0][n], 0, 0, 0);
        acc[1][n] = __builtin_amdgcn_mfma_f32_16x16x32_bf16(a1, bf, acc[1][n], 0, 0, 0);
      }
    }
  }
  __syncthreads();
  unsigned short* reg = ((wv < 2) ? lA : lB) + (wv & 1) * 4096;
  float bias[8];
#pragma unroll
  for (int n = 0; n < 8; ++n) bias[n] = b1[j0 + n * 16 + r16];
#pragma unroll
  for (int m = 0; m < 2; ++m)
#pragma unroll
    for (int n = 0; n < 8; ++n)
#pragma unroll
      for (int rg = 0; rg < 4; ++rg)
        reg[(m * 16 + quad * 4 + rg) * 128 + n * 16 + r16] =
            f2b(gelu_exact(acc[m][n][rg] + bias[n]));
#pragma unroll
  for (int it = 0; it < 8; ++it) {
    int flat = it * 64 + lane;
    int row = flat >> 4, c16 = flat & 15;
    uint4 v = *(const uint4*)&reg[row * 128 + c16 * 8];
    ntstore16(&t1[(size_t)(e0 + wv * 32 + row) * 512 + j0 + c16 * 8], v);
  }
}

// GEMM2: t1[E,512] @ wb2^T -> gelu -> t2[E,256] bf16. Frag-async, XCD swizzle.
__global__ __launch_bounds__(256) void k_mlp_gemm2(
    const unsigned short* __restrict__ t1, const unsigned short* __restrict__ wb2,
    const float* __restrict__ b2, unsigned short* __restrict__ t2) {
  __shared__ unsigned short lA[16 * 512];
  __shared__ unsigned short lB[16 * 512];
  const int b    = blockIdx.x;
  const int j0   = ((b >> 3) & 1) * 128;
  const int e0   = (((b >> 4) << 3) | (b & 7)) * 128;
  const int tid  = threadIdx.x;
  const int lane = tid & 63, wv = tid >> 6;
  const int r16  = lane & 15, quad = lane >> 4;

  const int row0 = e0 + wv * 32 + r16;
  const int row1 = row0 + 16;
  const unsigned short* pa0 = t1 + (size_t)row0 * 512 + quad * 8;
  const unsigned short* pa1 = t1 + (size_t)row1 * 512 + quad * 8;
  const unsigned short* pb0 = wb2 + (size_t)(j0 + (wv * 2 + 0) * 16 + r16) * 512 + quad * 8;
  const unsigned short* pb1 = wb2 + (size_t)(j0 + (wv * 2 + 1) * 16 + r16) * 512 + quad * 8;

  const f32x4 zz = {0.f, 0.f, 0.f, 0.f};
  f32x4 acc[2][8];
#pragma unroll
  for (int m = 0; m < 2; ++m)
#pragma unroll
    for (int n = 0; n < 8; ++n) acc[m][n] = zz;

  for (int ki = 0; ki < 8; ++ki) {
    __syncthreads();
#pragma unroll
    for (int kk = 0; kk < 2; ++kk) {
      gl2lds16(pa0 + ki * 64 + kk * 32, &lA[(wv * 4 + kk) * 512]);
      gl2lds16(pa1 + ki * 64 + kk * 32, &lA[(wv * 4 + 2 + kk) * 512]);
      gl2lds16(pb0 + ki * 64 + kk * 32, &lB[((wv * 2 + 0) * 2 + kk) * 512]);
      gl2lds16(pb1 + ki * 64 + kk * 32, &lB[((wv * 2 + 1) * 2 + kk) * 512]);
    }
    __builtin_amdgcn_s_waitcnt(0);
    __syncthreads();
#pragma unroll
    for (int kk = 0; kk < 2; ++kk) {
      bf16_8 a0 = frag16(&lA[(wv * 4 + kk) * 512 + lane * 8]);
      bf16_8 a1 = frag16(&lA[(wv * 4 + 2 + kk) * 512 + lane * 8]);
#pragma unroll
      for (int n = 0; n < 8; ++n) {
        bf16_8 bf = frag16(&lB[(n * 2 + kk) * 512 + lane * 8]);
        acc[0][n] = __builtin_amdgcn_mfma_f32_16x16x32_bf16(a0, bf, acc[0][n], 0, 0, 0);
        acc[1][n] = __builtin_amdgcn_mfma_f32_16x16x32_bf16(a1, bf, acc[1][n], 0, 0, 0);
      }
    }
  }
  __syncthreads();
  unsigned short* reg = ((wv < 2) ? lA : lB) + (wv & 1) * 4096;
  float bias[8];
#pragma unroll
  for (int n = 0; n < 8; ++n) bias[n] = b2[j0 + n * 16 + r16];
#pragma unroll
  for (int m = 0; m < 2; ++m)
#pragma unroll
    for (int n = 0; n < 8; ++n)
#pragma unroll
      for (int rg = 0; rg < 4; ++rg)
        reg[(m * 16 + quad * 4 + rg) * 128 + n * 16 + r16] =
            f2b(gelu_exact(acc[m][n][rg] + bias[n]));
#pragma unroll
  for (int it = 0; it < 8; ++it) {
    int flat = it * 64 + lane;
    int row = flat >> 4, c16 = flat & 15;
    uint4 v = *(const uint4*)&reg[row * 128 + c16 * 8];
    ntstore16(&t2[(size_t)(e0 + wv * 32 + row) * 256 + j0 + c16 * 8], v);
  }
}

__global__ __launch_bounds__(256) void k_mlp_gemm3(
    const unsigned short* __restrict__ t2, const unsigned short* __restrict__ wb3,
    const float* __restrict__ b3, float* __restrict__ dmo) {
  const int tid  = threadIdx.x;
  const int lane = tid & 63, wv = tid >> 6;
  const int r16  = lane & 15, quad = lane >> 4;
  const int eb   = blockIdx.x * 64 + wv * 16;
  const f32x4 zz = {0.f, 0.f, 0.f, 0.f};
  f32x4 acc = zz;
#pragma unroll
  for (int ks = 0; ks < 8; ++ks) {
    bf16_8 a = frag16(t2 + (size_t)(eb + r16) * 256 + ks * 32 + quad * 8);
    bf16_8 b = frag16(wb3 + (size_t)r16 * 256 + ks * 32 + quad * 8);
    acc = __builtin_amdgcn_mfma_f32_16x16x32_bf16(a, b, acc, 0, 0, 0);
  }
  float bb = b3[r16];
#pragma unroll
  for (int rg = 0; rg < 4; ++rg)
    dmo[(size_t)(eb + quad * 4 + rg) * DIN_ + r16] = acc[rg] + bb;
}

// ---------------- fused edge MLP (fallback path) ----------------
__global__ __launch_bounds__(256, 3) void k_edge_mlp_mfma(
    const float* __restrict__ xout, const int* __restrict__ adj,
    const float* __restrict__ dmap,
    const float* __restrict__ lin_w, const float* __restrict__ lin_b,
    const unsigned short* __restrict__ wb1, const float* __restrict__ b1,
    const unsigned short* __restrict__ wb2, const float* __restrict__ b2,
    const unsigned short* __restrict__ wb3, const float* __restrict__ b3,
    float* __restrict__ dmo) {
  __shared__ unsigned short sLo[8448];
  __shared__ unsigned short sT1[32][520];
  unsigned short (*sA)[136]  = (unsigned short(*)[136])sLo;
  unsigned short (*sT2)[264] = (unsigned short(*)[264])sLo;

  const int tid  = threadIdx.x;
  const int e0   = blockIdx.x * 32;
  const int lane = tid & 63;
  const int wv   = tid >> 6;
  const int r16  = lane & 15;
  const int quad = lane >> 4;

  const int sr = tid >> 3;
  const int t8 = tid & 7;
  const int se = e0 + sr;
  const int vsrc = adj[se];
  const int vdst = adj[E_ + se];

  float4 pf0, pf1, pf2, pf3;
  float4 dm0, dm1, dm2, dm3;
  {
    const float4* sp = (const float4*)(xout + (size_t)vsrc * D_ + t8 * 16);
    pf0 = sp[0]; pf1 = sp[1]; pf2 = sp[2]; pf3 = sp[3];
  }

  const f32x4 zz = {0.f, 0.f, 0.f, 0.f};
  f32x4 acc1[8][2];
#pragma unroll
  for (int i = 0; i < 8; ++i) { acc1[i][0] = zz; acc1[i][1] = zz; }

  for (int c = 0; c < 6; ++c) {
    const int k0 = c * 128;
    __syncthreads();
    {
      unsigned short tmp[16];
      if (c == 2 || c == 3) {
        int jb = (c - 2) * 128 + t8 * 16;
#pragma unroll
        for (int j = 0; j < 16; ++j) {
          const float4* lw = (const float4*)(lin_w + (size_t)(jb + j) * DIN_);
          float4 w0 = lw[0], w1 = lw[1], w2 = lw[2], w3 = lw[3];
          float acc = lin_b[jb + j];
          acc += dm0.x * w0.x + dm0.y * w0.y + dm0.z * w0.z + dm0.w * w0.w;
          acc += dm1.x * w1.x + dm1.y * w1.y + dm1.z * w1.z + dm1.w * w1.w;
          acc += dm2.x * w2.x + dm2.y * w2.y + dm2.z * w2.z + dm2.w * w2.w;
          acc += dm3.x * w3.x + dm3.y * w3.y + dm3.z * w3.z + dm3.w * w3.w;
          tmp[j] = f2b(acc);
        }
      } else {
        tmp[0]  = f2b(pf0.x); tmp[1]  = f2b(pf0.y); tmp[2]  = f2b(pf0.z); tmp[3]  = f2b(pf0.w);
        tmp[4]  = f2b(pf1.x); tmp[5]  = f2b(pf1.y); tmp[6]  = f2b(pf1.z); tmp[7]  = f2b(pf1.w);
        tmp[8]  = f2b(pf2.x); tmp[9]  = f2b(pf2.y); tmp[10] = f2b(pf2.z); tmp[11] = f2b(pf2.w);
        tmp[12] = f2b(pf3.x); tmp[13] = f2b(pf3.y); tmp[14] = f2b(pf3.z); tmp[15] = f2b(pf3.w);
      }
      unsigned short* dstp = &sA[sr][t8 * 16];
      uint4 q0v = {pack2(tmp[0], tmp[1]),   pack2(tmp[2], tmp[3]),
                   pack2(tmp[4], tmp[5]),   pack2(tmp[6], tmp[7])};
      uint4 q1v = {pack2(tmp[8], tmp[9]),   pack2(tmp[10], tmp[11]),
                   pack2(tmp[12], tmp[13]), pack2(tmp[14], tmp[15])};
      *(uint4*)(dstp) = q0v;
      *(uint4*)(dstp + 8) = q1v;
    }
    if (c == 0) {
      const float4* sp = (const float4*)(xout + (size_t)vsrc * D_ + 128 + t8 * 16);
      pf0 = sp[0]; pf1 = sp[1]; pf2 = sp[2]; pf3 = sp[3];
    } else if (c == 1) {
      const float4* dp = (const float4*)(dmap + (size_t)se * DIN_);
      dm0 = ntload4(dp); dm1 = ntload4(dp + 1); dm2 = ntload4(dp + 2); dm3 = ntload4(dp + 3);
    } else if (c == 3) {
      const float4* sp = (const float4*)(xout + (size_t)vdst * D_ + t8 * 16);
      pf0 = sp[0]; pf1 = sp[1]; pf2 = sp[2]; pf3 = sp[3];
    } else if (c == 4) {
      const float4* sp = (const float4*)(xout + (size_t)vdst * D_ + 128 + t8 * 16);
      pf0 = sp[0]; pf1 = sp[1]; pf2 = sp[2]; pf3 = sp[3];
    }
    __syncthreads();
#pragma unroll
    for (int kk = 0; kk < 4; ++kk) {
      bf16_8 a0 = frag16(&sA[r16][kk * 32 + quad * 8]);
      bf16_8 a1 = frag16(&sA[16 + r16][kk * 32 + quad * 8]);
#pragma unroll
      for (int i = 0; i < 8; ++i) {
        const unsigned short* bp =
            wb1 + (size_t)(wv * 128 + i * 16 + r16) * 768 + k0 + kk * 32 + quad * 8;
        bf16_8 bf = frag16(bp);
        acc1[i][0] = __builtin_amdgcn_mfma_f32_16x16x32_bf16(a0, bf, acc1[i][0], 0, 0, 0);
        acc1[i][1] = __builtin_amdgcn_mfma_f32_16x16x32_bf16(a1, bf, acc1[i][1], 0, 0, 0);
      }
    }
  }
#pragma unroll
  for (int i = 0; i < 8; ++i) {
    int col = wv * 128 + i * 16 + r16;
    float bb = b1[col];
#pragma unroll
    for (int m = 0; m < 2; ++m)
#pragma unroll
      for (int r = 0; r < 4; ++r) {
        int row = m * 16 + quad * 4 + r;
        sT1[row][col] = f2b(gelu_exact(acc1[i][m][r] + bb));
      }
  }
  __syncthreads();

  f32x4 acc2[4][2];
#pragma unroll
  for (int i = 0; i < 4; ++i) { acc2[i][0] = zz; acc2[i][1] = zz; }
#pragma unroll 4
  for (int ks = 0; ks < 16; ++ks) {
    bf16_8 a0 = frag16(&sT1[r16][ks * 32 + quad * 8]);
    bf16_8 a1 = frag16(&sT1[16 + r16][ks * 32 + quad * 8]);
#pragma unroll
    for (int i = 0; i < 4; ++i) {
      const unsigned short* bp =
          wb2 + (size_t)(wv * 64 + i * 16 + r16) * 512 + ks * 32 + quad * 8;
      bf16_8 bf = frag16(bp);
      acc2[i][0] = __builtin_amdgcn_mfma_f32_16x16x32_bf16(a0, bf, acc2[i][0], 0, 0, 0);
      acc2[i][1] = __builtin_amdgcn_mfma_f32_16x16x32_bf16(a1, bf, acc2[i][1], 0, 0, 0);
    }
  }
#pragma unroll
  for (int i = 0; i < 4; ++i) {
    int col = wv * 64 + i * 16 + r16;
    float bb = b2[col];
#pragma unroll
    for (int m = 0; m < 2; ++m)
#pragma unroll
      for (int r = 0; r < 4; ++r) {
        int row = m * 16 + quad * 4 + r;
        sT2[row][col] = f2b(gelu_exact(acc2[i][m][r] + bb));
      }
  }
  __syncthreads();

  if (wv < 2) {
    f32x4 acc3 = zz;
#pragma unroll
    for (int ks = 0; ks < 8; ++ks) {
      bf16_8 a = frag16(&sT2[wv * 16 + r16][ks * 32 + quad * 8]);
      bf16_8 b = frag16(wb3 + (size_t)r16 * 256 + ks * 32 + quad * 8);
      acc3 = __builtin_amdgcn_mfma_f32_16x16x32_bf16(a, b, acc3, 0, 0, 0);
    }
    float bb = b3[r16];
#pragma unroll
    for (int r = 0; r < 4; ++r) {
      int row = wv * 16 + quad * 4 + r;
      __builtin_nontemporal_store(acc3[r] + bb, &dmo[(size_t)(e0 + row) * DIN_ + r16]);
    }
  }
}

extern "C" void kernel_launch(void* const* d_in, const int* in_sizes, int n_in,
                              void* d_out, int out_size, void* d_ws, size_t ws_size,
                              hipStream_t stream) {
  const float* input = (const float*)d_in[0];
  const int*   adj   = (const int*)d_in[1];
  const float* h0    = (const float*)d_in[2];
  const void*  lamda = d_in[3];
  const float* alpha = (const float*)d_in[4];
  const void*  lll   = d_in[5];
  const float* dmap  = (const float*)d_in[6];
  const float* nrm   = (const float*)d_in[7];
  const float* Wl    = (const float*)d_in[8];
  const float* Wg    = (const float*)d_in[9];
  const float* lin_w = (const float*)d_in[10];
  const float* lin_b = (const float*)d_in[11];
  const float* w1    = (const float*)d_in[12];
  const float* b1    = (const float*)d_in[13];
  const float* w2    = (const float*)d_in[14];
  const float* b2    = (const float*)d_in[15];
  const float* w3    = (const float*)d_in[16];
  const float* b3    = (const float*)d_in[17];
  const float* ipw   = (const float*)d_in[18];
  const float* ipb   = (const float*)d_in[19];
  const float* opw   = (const float*)d_in[20];
  const float* opb   = (const float*)d_in[21];
  float* out = (float*)d_out;
  float* dmo = out + (size_t)N_ * D_;

  // ---- workspace layout ----
  float* ws   = (float*)d_ws;
  float* xout = ws;                               // N*D f32
  float* qkv  = xout + (size_t)N_ * D_;           // N*3D f32
  float* atto = qkv  + (size_t)N_ * 3 * D_;       // N*D f32
  float* hgl  = atto + (size_t)N_ * D_;           // N*D f32
  unsigned short* wb1 = (unsigned short*)(hgl + (size_t)N_ * D_);  // 512*768
  unsigned short* wb2 = wb1 + 512 * 768;          // 256*512
  unsigned short* wb3 = wb2 + 256 * 512;          // 16*256
  unsigned short* Qb  = wb3 + 16 * 256;           // 2*N*128
  unsigned short* Kb  = Qb + 2 * N_ * HD_;        // 2*N*128
  unsigned short* Vt  = Kb + 2 * N_ * HD_;        // 2*128*N
  unsigned short* t1b = Vt + 2 * HD_ * N_;        // E*512  (fast path only)
  unsigned short* t2b = t1b + (size_t)E_ * 512;   // E*256  (aliases eab; eab consumed first)
  unsigned short* eab = t2b;                      // E*256
  int* cnt  = (int*)(t2b + (size_t)E_ * 256);     // 4096
  int* off  = cnt + 4096;                         // 4097
  int* cur  = off + 4100;                         // 4096
  int* perm = cur + 4096;                         // E
  unsigned short* xbp = (unsigned short*)(perm + E_);  // N*D bf16
  unsigned short* lwb = xbp + (size_t)N_ * D_;    // 256*16 bf16 lin_w
  unsigned short* inb = lwb + 256 * DIN_;         // N*D bf16 input
  unsigned short* h0b = inb + (size_t)N_ * D_;    // N*D bf16 h0
  unsigned short* hgb = h0b + (size_t)N_ * D_;    // N*D bf16 h_global
  unsigned short* wqb = hgb + (size_t)N_ * D_;    // 768*256 bf16 in_proj
  unsigned short* wlT = wqb + 768 * 256;          // 256*512 bf16 Wl^T
  unsigned short* wgT = wlT + 256 * 512;          // 256*512 bf16 Wg^T
  unsigned short* opwb = wgT + 256 * 512;         // 256*256 bf16 out_proj
  unsigned short* attob = (unsigned short*)qkv;   // N*D bf16 (qkv region reused post-split)
  const size_t fast_need = (size_t)((char*)(opwb + 256 * 256) - (char*)d_ws);
  const bool fast = ws_size >= fast_need;

  // bf16 weight conversion (native [out,in] layout == MFMA B-frag layout)
  k_f2b<<<dim3((512 * 768 + 255) / 256), 256, 0, stream>>>(w1, wb1, 512 * 768);
  k_f2b<<<dim3((256 * 512 + 255) / 256), 256, 0, stream>>>(w2, wb2, 256 * 512);
  k_f2b<<<dim3((16 * 256 + 255) / 256), 256, 0, stream>>>(w3, wb3, 16 * 256);

  if (fast) {
    // weight/input preps for MFMA qkv + out_proj + final
    k_f2b<<<dim3(N_ * D_ / 256), 256, 0, stream>>>(input, inb, N_ * D_);
    k_f2b<<<dim3(N_ * D_ / 256), 256, 0, stream>>>(h0, h0b, N_ * D_);
    k_f2b<<<dim3((768 * 256 + 255) / 256), 256, 0, stream>>>(ipw, wqb, 768 * 256);
    k_f2b<<<dim3((256 * 256 + 255) / 256), 256, 0, stream>>>(opw, opwb, 256 * 256);
    k_tb<<<dim3((512 * 256 + 255) / 256), 256, 0, stream>>>(Wl, wlT, 512, 256);
    k_tb<<<dim3((512 * 256 + 255) / 256), 256, 0, stream>>>(Wg, wgT, 512, 256);

    // edge_attr via MFMA, CSR build, gather aggregation
    k_f2b<<<dim3((256 * DIN_ + 255) / 256), 256, 0, stream>>>(lin_w, lwb, 256 * DIN_);
    k_edge_attr_mfma<<<dim3(E_ / 64), 256, 0, stream>>>(dmap, lwb, lin_b, eab);
    k_zero<<<dim3(16), 256, 0, stream>>>(cnt, 4096);
    k_hist<<<dim3(E_ / 256), 256, 0, stream>>>(adj, cnt);
    k_scan<<<dim3(1), 1024, 0, stream>>>(cnt, off, cur);
    k_bucket<<<dim3(E_ / 256), 256, 0, stream>>>(adj, cur, perm);
    k_gather<<<dim3(N_), 256, 0, stream>>>(input, adj, eab, nrm, off, perm, xout);
    k_f2b<<<dim3(N_ * D_ / 256), 256, 0, stream>>>(xout, xbp, N_ * D_);

    // MHA: MFMA qkv -> split -> MFMA flash attn (dual out) -> MFMA out_proj
    k_qkv_mfma<<<dim3(192), 256, 0, stream>>>(inb, wqb, ipb, qkv);
    k_qk2b<<<dim3(N_ * 512 / 8 / 256), 256, 0, stream>>>(qkv, Qb, Kb);
    k_v2t<<<dim3(N_ / 64, 2), 256, 0, stream>>>(qkv, Vt);
    k_attn_mfma<<<dim3(N_ / 16, 2), 256, 0, stream>>>(Qb, Kb, Vt, atto, attob);
    k_outproj_mfma<<<dim3(64), 256, 0, stream>>>(attob, opwb, opb, hgl, hgb);

    // output[N,D] via MFMA
    k_final_mfma<<<dim3(64), 256, 0, stream>>>(xbp, h0b, hgb, wlT, wgT,
                                               xout, hgl, h0, alpha, lamda, lll, out);

    // dm_out[E,16]: gemm1 -> gemm2 (t2 aliases eab, consumed above) -> gemm3
    k_mlp_gemm1<<<dim3(4096), 256, 0, stream>>>(xbp, adj, eab, wb1, b1, t1b);
    k_mlp_gemm2<<<dim3(2048), 256, 0, stream>>>(t1b, wb2, b2, t2b);
    k_mlp_gemm3<<<dim3(E_ / 64), 256, 0, stream>>>(t2b, wb3, b3, dmo);
  } else {
    k_copy4<<<dim3(N_ * D_ / 4 / 256), 256, 0, stream>>>((const float4*)input, (float4*)xout,
                                                         N_ * D_ / 4);
    k_scatter<<<dim3(E_ / 4), 256, 0, stream>>>(input, adj, dmap, nrm, lin_w, lin_b, xout);
    k_gemm_bt<<<dim3(D3_ / 64, N_ / 64), 256, 0, stream>>>(input, ipw, ipb, qkv, N_, D3_, D_);
    k_qk2b<<<dim3(N_ * 512 / 8 / 256), 256, 0, stream>>>(qkv, Qb, Kb);
    k_v2t<<<dim3(N_ / 64, 2), 256, 0, stream>>>(qkv, Vt);
    k_attn_mfma<<<dim3(N_ / 16, 2), 256, 0, stream>>>(Qb, Kb, Vt, atto, (unsigned short*)qkv);
    k_gemm_bt<<<dim3(D_ / 64, N_ / 64), 256, 0, stream>>>(atto, opw, opb, hgl, N_, D_, D_);
    k_final<<<dim3(4, N_ / 64), 256, 0, stream>>>(xout, hgl, h0, Wl, Wg, alpha, lamda, lll, out);
    k_edge_mlp_mfma<<<dim3(E_ / 32), 256, 0, stream>>>(xout, adj, dmap, lin_w, lin_b,
                                                       wb1, b1, wb2, b2, wb3, b3, dmo);
  }
}

// Round 18
// 688.695 us; speedup vs baseline: 1.0741x; 1.0341x over previous
//
#include <hip/hip_runtime.h>
#include <hip/hip_bf16.h>
#include <math.h>

// Problem constants
constexpr int N_   = 4096;
constexpr int E_   = 131072;
constexpr int D_   = 256;
constexpr int DIN_ = 16;
constexpr int D3_  = 768;   // 3*D
constexpr int HD_  = 128;   // head dim

typedef __bf16 bf16_8 __attribute__((ext_vector_type(8)));
typedef float  f32x4  __attribute__((ext_vector_type(4)));
typedef float  f32x4v __attribute__((ext_vector_type(4)));
typedef unsigned int u32x4 __attribute__((ext_vector_type(4)));   // NT-store-compatible 16B

// ---- bf16 helpers ----
__device__ __forceinline__ unsigned short f2b(float f) {
  unsigned int u = __float_as_uint(f);
  u = u + 0x7fffu + ((u >> 16) & 1u);   // round-to-nearest-even
  return (unsigned short)(u >> 16);
}
__device__ __forceinline__ float b2f(unsigned short s) {
  return __uint_as_float(((unsigned int)s) << 16);
}
__device__ __forceinline__ unsigned int pack2(unsigned short lo, unsigned short hi) {
  return (unsigned int)lo | ((unsigned int)hi << 16);
}
__device__ __forceinline__ bf16_8 frag16(const unsigned short* p) {
  uint4 v = *(const uint4*)p;           // 16B load (LDS b128 or global dwordx4)
  return __builtin_bit_cast(bf16_8, v);
}
__device__ __forceinline__ float4 ntload4(const void* p) {
  f32x4v v = __builtin_nontemporal_load((const f32x4v*)p);
  float4 r;
  r.x = v[0]; r.y = v[1]; r.z = v[2]; r.w = v[3];
  return r;
}
__device__ __forceinline__ void ntstore16(void* dst, uint4 v) {
  __builtin_nontemporal_store(__builtin_bit_cast(u32x4, v), (u32x4*)dst);
}
// async global->LDS, 16B per lane; LDS dst = uniform base + lane*16
__device__ __forceinline__ void gl2lds16(const unsigned short* g, unsigned short* l) {
  __builtin_amdgcn_global_load_lds(
      (const __attribute__((address_space(1))) void*)g,
      (__attribute__((address_space(3))) void*)l, 16, 0, 0);
}

// Python scalar may arrive as int32 or float32 bits; values here are small ints.
__device__ __forceinline__ float scalar_as_float(const void* p) {
  int iv = *(const int*)p;
  if (iv >= 1 && iv <= 1000000) return (float)iv;  // plausible int
  return __int_as_float(iv);                       // else float bits
}

__device__ __forceinline__ float gelu_exact(float v) {
  return 0.5f * v * (1.0f + erff(v * 0.70710678118654752f));
}

// ---------------- f32 -> bf16 convert ----------------
__global__ void k_f2b(const float* __restrict__ src, unsigned short* __restrict__ dst, int n) {
  int i = blockIdx.x * 256 + threadIdx.x;
  if (i < n) dst[i] = f2b(src[i]);
}

// ---------------- merged weight converts (6 tensors, one launch) ----------------
__global__ void k_prep_w(const float* __restrict__ w1, const float* __restrict__ w2,
                         const float* __restrict__ w3, const float* __restrict__ lin_w,
                         const float* __restrict__ ipw, const float* __restrict__ opw,
                         unsigned short* __restrict__ wb1, unsigned short* __restrict__ wb2,
                         unsigned short* __restrict__ wb3, unsigned short* __restrict__ lwb,
                         unsigned short* __restrict__ wqb, unsigned short* __restrict__ opwb) {
  int i = blockIdx.x * 256 + threadIdx.x;
  if (i < 393216) { wb1[i] = f2b(w1[i]); return; }
  i -= 393216;
  if (i < 131072) { wb2[i] = f2b(w2[i]); return; }
  i -= 131072;
  if (i < 4096) { wb3[i] = f2b(w3[i]); return; }
  i -= 4096;
  if (i < 4096) { lwb[i] = f2b(lin_w[i]); return; }
  i -= 4096;
  if (i < 196608) { wqb[i] = f2b(ipw[i]); return; }
  i -= 196608;
  if (i < 65536) { opwb[i] = f2b(opw[i]); }
}

// ---------------- merged Wl/Wg transpose+convert ----------------
__global__ void k_prep_t(const float* __restrict__ Wl, const float* __restrict__ Wg,
                         unsigned short* __restrict__ wlT, unsigned short* __restrict__ wgT) {
  int i = blockIdx.x * 256 + threadIdx.x;          // 2 x 131072
  int seg = i >> 17;
  int idx = i & 131071;
  int k = idx & 511, j = idx >> 9;                 // dst [256][512] <- src [512][256]
  const float* src = seg ? Wg : Wl;
  unsigned short* dst = seg ? wgT : wlT;
  dst[idx] = f2b(src[(size_t)k * 256 + j]);
}

// ---------------- merged input/h0 converts ----------------
__global__ void k_prep_x(const float* __restrict__ input, const float* __restrict__ h0,
                         unsigned short* __restrict__ inb, unsigned short* __restrict__ h0b) {
  int i = blockIdx.x * 256 + threadIdx.x;          // 2 x 2^20
  int seg = i >> 20;
  int idx = i & 1048575;
  if (seg) h0b[idx] = f2b(h0[idx]);
  else     inb[idx] = f2b(input[idx]);
}

// ---------------- copy (float4) ----------------
__global__ void k_copy4(const float4* __restrict__ src, float4* __restrict__ dst, int n4) {
  int idx = blockIdx.x * 256 + threadIdx.x;
  if (idx < n4) dst[idx] = src[idx];
}

// ---------------- edge_attr via zero-padded MFMA ----------------
__global__ __launch_bounds__(256) void k_edge_attr_mfma(
    const float* __restrict__ dmap, const unsigned short* __restrict__ lwb,
    const float* __restrict__ lin_b, unsigned short* __restrict__ eab) {
  __shared__ unsigned short sT[4][16][264];   // per-wave C tile (bounce), 33 KB
  const int tid  = threadIdx.x;
  const int lane = tid & 63, wv = tid >> 6;
  const int r16  = lane & 15, quad = lane >> 4;
  const int e0   = blockIdx.x * 64 + wv * 16;

  const uint4 z4 = make_uint4(0u, 0u, 0u, 0u);
  bf16_8 bfr[16];
#pragma unroll
  for (int n = 0; n < 16; ++n) {
    uint4 v = z4;
    if (quad < 2) v = *(const uint4*)(lwb + (size_t)(n * 16 + r16) * DIN_ + quad * 8);
    bfr[n] = __builtin_bit_cast(bf16_8, v);
  }
  bf16_8 af;
  {
    uint4 p = z4;
    if (quad < 2) {
      const float4* dp = (const float4*)(dmap + (size_t)(e0 + r16) * DIN_ + quad * 8);
      float4 a = dp[0], b = dp[1];
      p = make_uint4(pack2(f2b(a.x), f2b(a.y)), pack2(f2b(a.z), f2b(a.w)),
                     pack2(f2b(b.x), f2b(b.y)), pack2(f2b(b.z), f2b(b.w)));
    }
    af = __builtin_bit_cast(bf16_8, p);
  }

  const f32x4 zz = {0.f, 0.f, 0.f, 0.f};
  f32x4 acc[16];
#pragma unroll
  for (int n = 0; n < 16; ++n) acc[n] = zz;
#pragma unroll
  for (int n = 0; n < 16; ++n)
    acc[n] = __builtin_amdgcn_mfma_f32_16x16x32_bf16(af, bfr[n], acc[n], 0, 0, 0);

#pragma unroll
  for (int n = 0; n < 16; ++n) {
    float bb = lin_b[n * 16 + r16];
#pragma unroll
    for (int rg = 0; rg < 4; ++rg)
      sT[wv][quad * 4 + rg][n * 16 + r16] = f2b(acc[n][rg] + bb);
  }
#pragma unroll
  for (int it = 0; it < 8; ++it) {
    int flat = it * 64 + lane;
    int row = flat >> 5, g = flat & 31;
    uint4 v = *(const uint4*)&sT[wv][row][g * 8];
    ntstore16(&eab[(size_t)(e0 + row) * D_ + g * 8], v);
  }
}

// ================= CSR build (per-launch) + gather aggregation =================
__global__ void k_zero(int* __restrict__ p, int n) {
  int i = blockIdx.x * 256 + threadIdx.x;
  if (i < n) p[i] = 0;
}
__global__ void k_hist(const int* __restrict__ adj, int* __restrict__ cnt) {
  int e = blockIdx.x * 256 + threadIdx.x;
  atomicAdd(&cnt[adj[E_ + e]], 1);
}
__global__ __launch_bounds__(1024) void k_scan(const int* __restrict__ cnt,
                                               int* __restrict__ off, int* __restrict__ cur) {
  __shared__ int ps[1024];
  int tid = threadIdx.x;
  int base = tid * 4;
  int a0 = cnt[base], a1 = cnt[base + 1], a2 = cnt[base + 2], a3 = cnt[base + 3];
  int tsum = a0 + a1 + a2 + a3;
  ps[tid] = tsum;
  __syncthreads();
  for (int st = 1; st < 1024; st <<= 1) {
    int v = (tid >= st) ? ps[tid - st] : 0;
    __syncthreads();
    ps[tid] += v;
    __syncthreads();
  }
  int excl = ps[tid] - tsum;
  int o0 = excl, o1 = excl + a0, o2 = o1 + a1, o3 = o2 + a2;
  off[base] = o0; off[base + 1] = o1; off[base + 2] = o2; off[base + 3] = o3;
  cur[base] = o0; cur[base + 1] = o1; cur[base + 2] = o2; cur[base + 3] = o3;
  if (tid == 1023) off[4096] = o3 + a3;
}
__global__ void k_bucket(const int* __restrict__ adj, int* __restrict__ cur,
                         int* __restrict__ perm) {
  int e = blockIdx.x * 256 + threadIdx.x;
  int p = atomicAdd(&cur[adj[E_ + e]], 1);
  perm[p] = e;
}
__global__ __launch_bounds__(256) void k_gather(
    const float* __restrict__ x, const int* __restrict__ adj,
    const unsigned short* __restrict__ eab, const float* __restrict__ nrm,
    const int* __restrict__ off, const int* __restrict__ perm,
    float* __restrict__ xout) {
  int n = blockIdx.x, t = threadIdx.x;
  int beg = off[n], end = off[n + 1];
  float acc = x[(size_t)n * D_ + t];
  int i = beg;
  for (; i + 1 < end; i += 2) {
    int e0 = perm[i], e1 = perm[i + 1];
    int s0 = adj[e0], s1 = adj[e1];
    float w0 = nrm[e0], w1 = nrm[e1];
    float xa = x[(size_t)s0 * D_ + t];
    float xb = x[(size_t)s1 * D_ + t];
    float ea0 = b2f(eab[(size_t)e0 * D_ + t]);
    float ea1 = b2f(eab[(size_t)e1 * D_ + t]);
    acc += w0 * (xa + ea0) + w1 * (xb + ea1);
  }
  if (i < end) {
    int e0 = perm[i];
    int s0 = adj[e0];
    float w0 = nrm[e0];
    acc += w0 * (x[(size_t)s0 * D_ + t] + b2f(eab[(size_t)e0 * D_ + t]));
  }
  xout[(size_t)n * D_ + t] = acc;
}

// ---------------- legacy scatter (fallback path) ----------------
__global__ __launch_bounds__(256) void k_scatter(
    const float* __restrict__ x, const int* __restrict__ adj,
    const float* __restrict__ dmap, const float* __restrict__ nrm,
    const float* __restrict__ lin_w, const float* __restrict__ lin_b,
    float* __restrict__ xout) {
  __shared__ float s_dm[4][DIN_];
  int te = threadIdx.x >> 6;
  int d4 = threadIdx.x & 63;
  int e  = blockIdx.x * 4 + te;
  if (d4 < DIN_) s_dm[te][d4] = dmap[(size_t)e * DIN_ + d4];
  __syncthreads();
  int vs = adj[e];
  int vd = adj[E_ + e];
  float w = nrm[e];
  int d = d4 * 4;
  float4 xs = *(const float4*)(x + (size_t)vs * D_ + d);
  float ea[4];
#pragma unroll
  for (int q = 0; q < 4; q++) {
    const float* lw = lin_w + (size_t)(d + q) * DIN_;
    float acc = lin_b[d + q];
#pragma unroll
    for (int k = 0; k < DIN_; k++) acc += s_dm[te][k] * lw[k];
    ea[q] = acc;
  }
  float* op = xout + (size_t)vd * D_ + d;
  atomicAdd(op + 0, w * (xs.x + ea[0]));
  atomicAdd(op + 1, w * (xs.y + ea[1]));
  atomicAdd(op + 2, w * (xs.z + ea[2]));
  atomicAdd(op + 3, w * (xs.w + ea[3]));
}

// ---------------- C[M,N] = A[M,K] @ B[N,K]^T + bias (fp32, fallback) ----------------
__global__ __launch_bounds__(256) void k_gemm_bt(
    const float* __restrict__ A, const float* __restrict__ B,
    const float* __restrict__ bias, float* __restrict__ C,
    int M, int Nn, int K) {
  __shared__ float sA[16][68];
  __shared__ float sB[16][68];
  int bm = blockIdx.y * 64, bn = blockIdx.x * 64;
  int tid = threadIdx.x;
  int tr = tid >> 4, tc = tid & 15;
  float acc[4][4] = {};
  for (int k0 = 0; k0 < K; k0 += 16) {
    for (int i = tid; i < 1024; i += 256) {
      int r = i >> 4, c = i & 15;
      sA[c][r] = A[(size_t)(bm + r) * K + k0 + c];
      sB[c][r] = B[(size_t)(bn + r) * K + k0 + c];
    }
    __syncthreads();
#pragma unroll
    for (int kk = 0; kk < 16; kk++) {
      float av[4], bv[4];
#pragma unroll
      for (int i = 0; i < 4; i++) av[i] = sA[kk][tr * 4 + i];
#pragma unroll
      for (int j = 0; j < 4; j++) bv[j] = sB[kk][tc * 4 + j];
#pragma unroll
      for (int i = 0; i < 4; i++)
#pragma unroll
        for (int j = 0; j < 4; j++) acc[i][j] += av[i] * bv[j];
    }
    __syncthreads();
  }
#pragma unroll
  for (int i = 0; i < 4; i++) {
    int r = bm + tr * 4 + i;
#pragma unroll
    for (int j = 0; j < 4; j++) {
      int c = bn + tc * 4 + j;
      C[(size_t)r * Nn + c] = acc[i][j] + bias[c];
    }
  }
}

// ---------------- qkv proj via MFMA: bf16 in, fp32 qkv out ----------------
__global__ __launch_bounds__(256) void k_qkv_mfma(
    const unsigned short* __restrict__ inb, const unsigned short* __restrict__ wqb,
    const float* __restrict__ ipb, float* __restrict__ qkv) {
  __shared__ unsigned short sA[128][72];
  __shared__ unsigned short sB[128][72];
  const int b   = blockIdx.x;
  const int j0  = (b % 6) * 128;
  const int m0  = (b / 6) * 128;
  const int tid = threadIdx.x;
  const int lane = tid & 63, wv = tid >> 6;
  const int r16  = lane & 15, quad = lane >> 4;
  const int sr   = tid >> 1, sh = (tid & 1) * 32;

  const unsigned short* ra = inb + (size_t)(m0 + sr) * D_;
  const unsigned short* rb = wqb + (size_t)(j0 + sr) * D_;

  const f32x4 zz = {0.f, 0.f, 0.f, 0.f};
  f32x4 acc[2][8];
#pragma unroll
  for (int m = 0; m < 2; ++m)
#pragma unroll
    for (int n = 0; n < 8; ++n) acc[m][n] = zz;

  for (int ki = 0; ki < 4; ++ki) {
    __syncthreads();
    {
      const uint4* s    = (const uint4*)(ra + ki * 64 + sh);
      const uint4* bsrc = (const uint4*)(rb + ki * 64 + sh);
      uint4* da = (uint4*)&sA[sr][sh];
      uint4* db = (uint4*)&sB[sr][sh];
#pragma unroll
      for (int i = 0; i < 4; ++i) { da[i] = s[i]; db[i] = bsrc[i]; }
    }
    __syncthreads();
#pragma unroll
    for (int kk = 0; kk < 2; ++kk) {
      bf16_8 a0 = frag16(&sA[wv * 32 + r16][kk * 32 + quad * 8]);
      bf16_8 a1 = frag16(&sA[wv * 32 + 16 + r16][kk * 32 + quad * 8]);
#pragma unroll
      for (int n = 0; n < 8; ++n) {
        bf16_8 bf = frag16(&sB[n * 16 + r16][kk * 32 + quad * 8]);
        acc[0][n] = __builtin_amdgcn_mfma_f32_16x16x32_bf16(a0, bf, acc[0][n], 0, 0, 0);
        acc[1][n] = __builtin_amdgcn_mfma_f32_16x16x32_bf16(a1, bf, acc[1][n], 0, 0, 0);
      }
    }
  }
#pragma unroll
  for (int m = 0; m < 2; ++m)
#pragma unroll
    for (int n = 0; n < 8; ++n) {
      int col = j0 + n * 16 + r16;
      float bb = ipb[col];
#pragma unroll
      for (int rg = 0; rg < 4; ++rg) {
        int row = m0 + wv * 32 + m * 16 + quad * 4 + rg;
        qkv[(size_t)row * D3_ + col] = acc[m][n][rg] + bb;
      }
    }
}

// ---------------- out_proj via MFMA: hgl = attob @ opwb^T + opb; hgb = bf16 ----
__global__ __launch_bounds__(256) void k_outproj_mfma(
    const unsigned short* __restrict__ attob, const unsigned short* __restrict__ opwb,
    const float* __restrict__ opb, float* __restrict__ hgl,
    unsigned short* __restrict__ hgb) {
  __shared__ unsigned short sA[128][72];
  __shared__ unsigned short sB[128][72];
  const int b   = blockIdx.x;
  const int j0  = (b & 1) * 128;
  const int m0  = (b >> 1) * 128;
  const int tid = threadIdx.x;
  const int lane = tid & 63, wv = tid >> 6;
  const int r16  = lane & 15, quad = lane >> 4;
  const int sr   = tid >> 1, sh = (tid & 1) * 32;

  const unsigned short* ra = attob + (size_t)(m0 + sr) * D_;
  const unsigned short* rb = opwb + (size_t)(j0 + sr) * D_;

  const f32x4 zz = {0.f, 0.f, 0.f, 0.f};
  f32x4 acc[2][8];
#pragma unroll
  for (int m = 0; m < 2; ++m)
#pragma unroll
    for (int n = 0; n < 8; ++n) acc[m][n] = zz;

  for (int ki = 0; ki < 4; ++ki) {
    __syncthreads();
    {
      const uint4* s    = (const uint4*)(ra + ki * 64 + sh);
      const uint4* bsrc = (const uint4*)(rb + ki * 64 + sh);
      uint4* da = (uint4*)&sA[sr][sh];
      uint4* db = (uint4*)&sB[sr][sh];
#pragma unroll
      for (int i = 0; i < 4; ++i) { da[i] = s[i]; db[i] = bsrc[i]; }
    }
    __syncthreads();
#pragma unroll
    for (int kk = 0; kk < 2; ++kk) {
      bf16_8 a0 = frag16(&sA[wv * 32 + r16][kk * 32 + quad * 8]);
      bf16_8 a1 = frag16(&sA[wv * 32 + 16 + r16][kk * 32 + quad * 8]);
#pragma unroll
      for (int n = 0; n < 8; ++n) {
        bf16_8 bf = frag16(&sB[n * 16 + r16][kk * 32 + quad * 8]);
        acc[0][n] = __builtin_amdgcn_mfma_f32_16x16x32_bf16(a0, bf, acc[0][n], 0, 0, 0);
        acc[1][n] = __builtin_amdgcn_mfma_f32_16x16x32_bf16(a1, bf, acc[1][n], 0, 0, 0);
      }
    }
  }
#pragma unroll
  for (int m = 0; m < 2; ++m)
#pragma unroll
    for (int n = 0; n < 8; ++n) {
      int col = j0 + n * 16 + r16;
      float bb = opb[col];
#pragma unroll
      for (int rg = 0; rg < 4; ++rg) {
        int row = m0 + wv * 32 + m * 16 + quad * 4 + rg;
        float v = acc[m][n][rg] + bb;
        size_t idx = (size_t)row * D_ + col;
        hgl[idx] = v;
        hgb[idx] = f2b(v);
      }
    }
}

// ---------------- final combine via MFMA ----------------
__global__ __launch_bounds__(256) void k_final_mfma(
    const unsigned short* __restrict__ xbp, const unsigned short* __restrict__ h0b,
    const unsigned short* __restrict__ hgb,
    const unsigned short* __restrict__ wlT, const unsigned short* __restrict__ wgT,
    const float* __restrict__ hl, const float* __restrict__ hg, const float* __restrict__ h0,
    const float* __restrict__ alpha_p, const void* lamda_p, const void* l_p,
    float* __restrict__ out) {
  __shared__ unsigned short sA[128][72];
  __shared__ unsigned short sB[128][72];
  const int b   = blockIdx.x;
  const int j0  = (b & 1) * 128;
  const int m0  = (b >> 1) * 128;
  const int tid = threadIdx.x;
  const int lane = tid & 63, wv = tid >> 6;
  const int r16  = lane & 15, quad = lane >> 4;
  const int sr   = tid >> 1, sh = (tid & 1) * 32;

  const f32x4 zz = {0.f, 0.f, 0.f, 0.f};
  f32x4 acc[2][8];
#pragma unroll
  for (int m = 0; m < 2; ++m)
#pragma unroll
    for (int n = 0; n < 8; ++n) acc[m][n] = zz;

  const size_t arow = (size_t)(m0 + sr) * D_;
  const size_t brow = (size_t)(j0 + sr) * 512;

  for (int ki = 0; ki < 16; ++ki) {
    __syncthreads();
    {
      const int gc = ki * 64 + sh;
      const unsigned short* ap =
          (gc < 256) ? xbp + arow + gc
        : (gc < 512) ? h0b + arow + (gc - 256)
        : (gc < 768) ? hgb + arow + (gc - 512)
                     : h0b + arow + (gc - 768);
      const unsigned short* bp = (gc < 512) ? wlT + brow + gc : wgT + brow + (gc - 512);
      const uint4* s    = (const uint4*)ap;
      const uint4* bsrc = (const uint4*)bp;
      uint4* da = (uint4*)&sA[sr][sh];
      uint4* db = (uint4*)&sB[sr][sh];
#pragma unroll
      for (int i = 0; i < 4; ++i) { da[i] = s[i]; db[i] = bsrc[i]; }
    }
    __syncthreads();
#pragma unroll
    for (int kk = 0; kk < 2; ++kk) {
      bf16_8 a0 = frag16(&sA[wv * 32 + r16][kk * 32 + quad * 8]);
      bf16_8 a1 = frag16(&sA[wv * 32 + 16 + r16][kk * 32 + quad * 8]);
#pragma unroll
      for (int n = 0; n < 8; ++n) {
        bf16_8 bf = frag16(&sB[n * 16 + r16][kk * 32 + quad * 8]);
        acc[0][n] = __builtin_amdgcn_mfma_f32_16x16x32_bf16(a0, bf, acc[0][n], 0, 0, 0);
        acc[1][n] = __builtin_amdgcn_mfma_f32_16x16x32_bf16(a1, bf, acc[1][n], 0, 0, 0);
      }
    }
  }
  float theta = fminf(1.f, logf(scalar_as_float(lamda_p) / scalar_as_float(l_p) + 1.f));
  float a = alpha_p[0];
  float omt = 1.f - theta;
#pragma unroll
  for (int m = 0; m < 2; ++m)
#pragma unroll
    for (int n = 0; n < 8; ++n) {
      int col = j0 + n * 16 + r16;
#pragma unroll
      for (int rg = 0; rg < 4; ++rg) {
        int row = m0 + wv * 32 + m * 16 + quad * 4 + rg;
        size_t idx = (size_t)row * D_ + col;
        out[idx] = theta * acc[m][n][rg] +
                   omt * ((1.f - a) * (hl[idx] + hg[idx]) + 2.f * a * h0[idx]);
      }
    }
}

// ---------------- qkv split: fp32 [N,768] -> bf16 Qb/Kb [h][n][128] ----------------
__global__ void k_qk2b(const float* __restrict__ qkv,
                       unsigned short* __restrict__ Qb, unsigned short* __restrict__ Kb) {
  int off = (blockIdx.x * 256 + threadIdx.x) * 8;   // over N*512
  int n = off >> 9, c = off & 511;
  const float* src = qkv + (size_t)n * D3_ + c;     // Q cols 0..255, K cols 256..511
  float4 a = *(const float4*)src;
  float4 b = *(const float4*)(src + 4);
  uint4 p = {pack2(f2b(a.x), f2b(a.y)), pack2(f2b(a.z), f2b(a.w)),
             pack2(f2b(b.x), f2b(b.y)), pack2(f2b(b.z), f2b(b.w))};
  int cc = c & 255;
  int hh = cc >> 7, d = cc & 127;
  unsigned short* dst = (c < 256 ? Qb : Kb) + (size_t)hh * N_ * HD_ + (size_t)n * HD_ + d;
  *(uint4*)dst = p;
}

// ---------------- V transpose: fp32 qkv V-cols -> bf16 Vt [h][128][N] ----------------
__global__ __launch_bounds__(256) void k_v2t(const float* __restrict__ qkv,
                                             unsigned short* __restrict__ Vt) {
  __shared__ unsigned short sv[64][136];
  int h = blockIdx.y;
  int n0 = blockIdx.x * 64;
  int tid = threadIdx.x;
#pragma unroll
  for (int it = 0; it < 4; ++it) {
    int off = (tid + it * 256) * 8;
    int r = off >> 7, d = off & 127;
    const float* src = qkv + (size_t)(n0 + r) * D3_ + 2 * D_ + h * HD_ + d;
    float4 a = *(const float4*)src;
    float4 b = *(const float4*)(src + 4);
    uint4 p = {pack2(f2b(a.x), f2b(a.y)), pack2(f2b(a.z), f2b(a.w)),
               pack2(f2b(b.x), f2b(b.y)), pack2(f2b(b.z), f2b(b.w))};
    *(uint4*)&sv[r][d] = p;
  }
  __syncthreads();
#pragma unroll
  for (int it = 0; it < 4; ++it) {
    int off = (tid + it * 256) * 8;
    int d = off >> 6, k = off & 63;
    unsigned short t[8];
#pragma unroll
    for (int j = 0; j < 8; ++j) t[j] = sv[k + j][d];
    uint4 p = {pack2(t[0], t[1]), pack2(t[2], t[3]),
               pack2(t[4], t[5]), pack2(t[6], t[7])};
    *(uint4*)(Vt + (size_t)h * HD_ * N_ + (size_t)d * N_ + n0 + k) = p;
  }
}

// ---------------- MFMA flash attention, H=2, HD=128 (dual fp32+bf16 out) ----------------
__global__ __launch_bounds__(256) void k_attn_mfma(
    const unsigned short* __restrict__ Qb, const unsigned short* __restrict__ Kb,
    const unsigned short* __restrict__ Vt, float* __restrict__ o_out,
    unsigned short* __restrict__ ob) {
  __shared__ unsigned short sK[64][136];   // keys x dims (+8 pad)
  __shared__ unsigned short sV[128][72];   // dims x keys (+8 pad)
  __shared__ float          sS[16][68];    // scores
  __shared__ unsigned short sP[16][72];    // probs bf16 (A-frag layout)
  __shared__ float sm[16], sl[16], sa[16];

  const int tid  = threadIdx.x;
  const int h    = blockIdx.y;
  const int q0   = blockIdx.x * 16;
  const int lane = tid & 63;
  const int wv   = tid >> 6;
  const int r16  = lane & 15;
  const int quad = lane >> 4;

  bf16_8 qf[4];
#pragma unroll
  for (int kk = 0; kk < 4; ++kk)
    qf[kk] = frag16(Qb + (size_t)h * N_ * HD_ + (size_t)(q0 + r16) * HD_ + kk * 32 + quad * 8);

  if (tid < 16) { sm[tid] = -1e30f; sl[tid] = 0.f; }

  const f32x4 zz = {0.f, 0.f, 0.f, 0.f};
  f32x4 o0 = zz, o1 = zz;

  const unsigned short* Kh = Kb + (size_t)h * N_ * HD_;
  const unsigned short* Vh = Vt + (size_t)h * HD_ * N_;

  for (int c0 = 0; c0 < N_; c0 += 64) {
    __syncthreads();
#pragma unroll
    for (int it = 0; it < 4; ++it) {
      int off = (tid + it * 256) * 8;
      int key = off >> 7, d = off & 127;
      *(uint4*)&sK[key][d] = *(const uint4*)(Kh + (size_t)(c0 + key) * HD_ + d);
    }
#pragma unroll
    for (int it = 0; it < 4; ++it) {
      int off = (tid + it * 256) * 8;
      int d = off >> 6, k = off & 63;
      *(uint4*)&sV[d][k] = *(const uint4*)(Vh + (size_t)d * N_ + c0 + k);
    }
    __syncthreads();
    f32x4 s = zz;
#pragma unroll
    for (int kk = 0; kk < 4; ++kk) {
      bf16_8 bf = frag16(&sK[wv * 16 + r16][kk * 32 + quad * 8]);
      s = __builtin_amdgcn_mfma_f32_16x16x32_bf16(qf[kk], bf, s, 0, 0, 0);
    }
    const float sc = 0.08838834764831845f;   // 1/sqrt(128)
#pragma unroll
    for (int r = 0; r < 4; ++r)
      sS[quad * 4 + r][wv * 16 + r16] = s[r] * sc;
    __syncthreads();
    {
      int row = tid >> 4, i = tid & 15;
      float4 v = *(const float4*)&sS[row][i * 4];
      float mx = fmaxf(fmaxf(v.x, v.y), fmaxf(v.z, v.w));
#pragma unroll
      for (int m = 1; m <= 8; m <<= 1) mx = fmaxf(mx, __shfl_xor(mx, m));
      float mo = sm[row];
      float mn = fmaxf(mo, mx);
      float p0 = __expf(v.x - mn), p1 = __expf(v.y - mn);
      float p2 = __expf(v.z - mn), p3 = __expf(v.w - mn);
      float ps = p0 + p1 + p2 + p3;
#pragma unroll
      for (int m = 1; m <= 8; m <<= 1) ps += __shfl_xor(ps, m);
      uint2 pk = {pack2(f2b(p0), f2b(p1)), pack2(f2b(p2), f2b(p3))};
      *(uint2*)&sP[row][i * 4] = pk;
      if (i == 0) {
        float al = __expf(mo - mn);
        sl[row] = sl[row] * al + ps;
        sm[row] = mn;
        sa[row] = al;
      }
    }
    __syncthreads();
    {
      float al0 = sa[quad * 4 + 0], al1 = sa[quad * 4 + 1];
      float al2 = sa[quad * 4 + 2], al3 = sa[quad * 4 + 3];
      o0[0] *= al0; o0[1] *= al1; o0[2] *= al2; o0[3] *= al3;
      o1[0] *= al0; o1[1] *= al1; o1[2] *= al2; o1[3] *= al3;
#pragma unroll
      for (int kk = 0; kk < 2; ++kk) {
        bf16_8 pa = frag16(&sP[r16][kk * 32 + quad * 8]);
        bf16_8 v0 = frag16(&sV[wv * 32 + r16][kk * 32 + quad * 8]);
        bf16_8 v1 = frag16(&sV[wv * 32 + 16 + r16][kk * 32 + quad * 8]);
        o0 = __builtin_amdgcn_mfma_f32_16x16x32_bf16(pa, v0, o0, 0, 0, 0);
        o1 = __builtin_amdgcn_mfma_f32_16x16x32_bf16(pa, v1, o1, 0, 0, 0);
      }
    }
  }
  {
    float i0 = 1.f / sl[quad * 4 + 0], i1 = 1.f / sl[quad * 4 + 1];
    float i2 = 1.f / sl[quad * 4 + 2], i3 = 1.f / sl[quad * 4 + 3];
    float vv[8];
    vv[0] = o0[0] * i0; vv[1] = o0[1] * i1; vv[2] = o0[2] * i2; vv[3] = o0[3] * i3;
    vv[4] = o1[0] * i0; vv[5] = o1[1] * i1; vv[6] = o1[2] * i2; vv[7] = o1[3] * i3;
#pragma unroll
    for (int g = 0; g < 2; ++g)
#pragma unroll
      for (int rg = 0; rg < 4; ++rg) {
        size_t idx = (size_t)(q0 + quad * 4 + rg) * D_ + h * HD_ + wv * 32 + g * 16 + r16;
        float v = vv[g * 4 + rg];
        o_out[idx] = v;
        ob[idx] = f2b(v);
      }
  }
}

// ---------------- final combine (fp32, fallback) ----------------
__global__ __launch_bounds__(256) void k_final(
    const float* __restrict__ hl, const float* __restrict__ hg, const float* __restrict__ h0,
    const float* __restrict__ Wl, const float* __restrict__ Wg,
    const float* __restrict__ alpha_p, const void* lamda_p, const void* l_p,
    float* __restrict__ out) {
  __shared__ float sA[16][68];
  __shared__ float sB[16][68];
  float theta = fminf(1.f, logf(scalar_as_float(lamda_p) / scalar_as_float(l_p) + 1.f));
  float a = alpha_p[0];
  int bm = blockIdx.y * 64, bn = blockIdx.x * 64;
  int tid = threadIdx.x, tr = tid >> 4, tc = tid & 15;
  float acc[4][4] = {};
  for (int k0 = 0; k0 < 1024; k0 += 16) {
    for (int i = tid; i < 1024; i += 256) {
      int r = i >> 4, c = i & 15;
      int k = k0 + c;
      const float* src = (k < 256) ? hl : (k < 512) ? h0 : (k < 768) ? hg : h0;
      sA[c][r] = src[(size_t)(bm + r) * 256 + (k & 255)];
    }
    for (int i = tid; i < 1024; i += 256) {
      int kk = i >> 6, j = i & 63;
      int k = k0 + kk;
      const float* Bp = (k < 512) ? (Wl + (size_t)k * 256) : (Wg + (size_t)(k - 512) * 256);
      sB[kk][j] = Bp[bn + j];
    }
    __syncthreads();
#pragma unroll
    for (int kk = 0; kk < 16; kk++) {
      float av[4], bv[4];
#pragma unroll
      for (int i = 0; i < 4; i++) av[i] = sA[kk][tr * 4 + i];
#pragma unroll
      for (int j = 0; j < 4; j++) bv[j] = sB[kk][tc * 4 + j];
#pragma unroll
      for (int i = 0; i < 4; i++)
#pragma unroll
        for (int j = 0; j < 4; j++) acc[i][j] += av[i] * bv[j];
    }
    __syncthreads();
  }
  float omt = 1.f - theta;
#pragma unroll
  for (int i = 0; i < 4; i++) {
    int r = bm + tr * 4 + i;
#pragma unroll
    for (int j = 0; j < 4; j++) {
      int c = bn + tc * 4 + j;
      size_t idx = (size_t)r * 256 + c;
      out[idx] = theta * acc[i][j] + omt * ((1.f - a) * (hl[idx] + hg[idx]) + 2.f * a * h0[idx]);
    }
  }
}

// ================= edge MLP as tiled GEMMs (fast path) =================
// GEMM1: h3[E,768] @ wb1^T -> gelu -> t1[E,512] bf16. 128x128 tile, BK=64.
__global__ __launch_bounds__(256) void k_mlp_gemm1(
    const unsigned short* __restrict__ xb, const int* __restrict__ adj,
    const unsigned short* __restrict__ eab, const unsigned short* __restrict__ wb1,
    const float* __restrict__ b1, unsigned short* __restrict__ t1) {
  __shared__ unsigned short lA[16 * 512];   // 16 A-frags x 1KB
  __shared__ unsigned short lB[16 * 512];   // 16 B-frags x 1KB
  const int b    = blockIdx.x;
  const int j0   = ((b >> 3) & 3) * 128;
  const int e0   = (((b >> 5) << 3) | (b & 7)) * 128;
  const int tid  = threadIdx.x;
  const int lane = tid & 63, wv = tid >> 6;
  const int r16  = lane & 15, quad = lane >> 4;

  const int row0 = e0 + wv * 32 + r16;
  const int row1 = row0 + 16;
  const int vs0 = adj[row0], vs1 = adj[row1];
  const int vd0 = adj[E_ + row0], vd1 = adj[E_ + row1];
  const unsigned short* pb0 = wb1 + (size_t)(j0 + (wv * 2 + 0) * 16 + r16) * 768 + quad * 8;
  const unsigned short* pb1 = wb1 + (size_t)(j0 + (wv * 2 + 1) * 16 + r16) * 768 + quad * 8;

  const f32x4 zz = {0.f, 0.f, 0.f, 0.f};
  f32x4 acc[2][8];
#pragma unroll
  for (int m = 0; m < 2; ++m)
#pragma unroll
    for (int n = 0; n < 8; ++n) acc[m][n] = zz;

  for (int ki = 0; ki < 12; ++ki) {
    __syncthreads();
    {
      const int seg = ki >> 2;
      const int col = (ki & 3) * 64 + quad * 8;
      const unsigned short* ap0;
      const unsigned short* ap1;
      if (seg == 1) {
        ap0 = eab + (size_t)row0 * D_;
        ap1 = eab + (size_t)row1 * D_;
      } else {
        int n0 = (seg == 0) ? vs0 : vd0;
        int n1 = (seg == 0) ? vs1 : vd1;
        ap0 = xb + (size_t)n0 * D_;
        ap1 = xb + (size_t)n1 * D_;
      }
#pragma unroll
      for (int kk = 0; kk < 2; ++kk) {
        gl2lds16(ap0 + col + kk * 32, &lA[(wv * 4 + kk) * 512]);
        gl2lds16(ap1 + col + kk * 32, &lA[(wv * 4 + 2 + kk) * 512]);
        gl2lds16(pb0 + ki * 64 + kk * 32, &lB[((wv * 2 + 0) * 2 + kk) * 512]);
        gl2lds16(pb1 + ki * 64 + kk * 32, &lB[((wv * 2 + 1) * 2 + kk) * 512]);
      }
    }
    __builtin_amdgcn_s_waitcnt(0);
    __syncthreads();
#pragma unroll
    for (int kk = 0; kk < 2; ++kk) {
      bf16_8 a0 = frag16(&lA[(wv * 4 + kk) * 512 + lane * 8]);
      bf16_8 a1 = frag16(&lA[(wv * 4 + 2 + kk) * 512 + lane * 8]);
#pragma unroll
      for (int n = 0; n < 8; ++n) {
        bf16_8 bf = frag16(&lB[(n * 2 + kk) * 512 + lane * 8]);
        acc[0][n] = __builtin_amdgcn_mfma_f32_16x16x32_bf16(a0, bf, acc[0][n], 0, 0, 0);
        acc[1][n] = __builtin_amdgcn_mfma_f32_16x16x32_bf16(a1, bf, acc[1][n], 0, 0, 0);
      }
    }
  }
  __syncthreads();
  unsigned short* reg = ((wv < 2) ? lA : lB) + (wv & 1) * 4096;
  float bias[8];
#pragma unroll
  for (int n = 0; n < 8; ++n) bias[n] = b1[j0 + n * 16 + r16];
#pragma unroll
  for (int m = 0; m < 2; ++m)
#pragma unroll
    for (int n = 0; n < 8; ++n)
#pragma unroll
      for (int rg = 0; rg < 4; ++rg)
        reg[(m * 16 + quad * 4 + rg) * 128 + n * 16 + r16] =
            f2b(gelu_exact(acc[m][n][rg] + bias[n]));
#pragma unroll
  for (int it = 0; it < 8; ++it) {
    int flat = it * 64 + lane;
    int row = flat >> 4, c16 = flat & 15;
    uint4 v = *(const uint4*)&reg[row * 128 + c16 * 8];
    ntstore16(&t1[(size_t)(e0 + wv * 32 + row) * 512 + j0 + c16 * 8], v);
  }
}

// GEMM2+3 fused (R18): t1[E,512] @ wb2^T -> gelu -> t2 (LDS only) -> @ wb3^T -> dmo.
// M=128/block (R16 lesson: M=64 halved B amortization), full N=256 in-register
// (acc[2][16] = 128 VGPRs; launch_bounds(256,2) allows <=256 VGPR, no spill).
// gemm3 reads t2 from PADDED stride-264 per-wave scratch (R16's stride-256
// scratch had a 16-way bank conflict in the A-frag reads).
__global__ __launch_bounds__(256, 2) void k_mlp_gemm23(
    const unsigned short* __restrict__ t1, const unsigned short* __restrict__ wb2,
    const float* __restrict__ b2, const unsigned short* __restrict__ wb3,
    const float* __restrict__ b3, float* __restrict__ dmo) {
  __shared__ unsigned short shm[24576];   // 48 KB: lA [0,8192) lB [8192,24576)
  unsigned short* lA = shm;
  unsigned short* lB = shm + 8192;
  const int e0   = blockIdx.x * 128;
  const int tid  = threadIdx.x;
  const int lane = tid & 63, wv = tid >> 6;
  const int r16  = lane & 15, quad = lane >> 4;

  const int row0 = e0 + wv * 32 + r16;
  const int row1 = row0 + 16;
  const unsigned short* pa0 = t1 + (size_t)row0 * 512 + quad * 8;
  const unsigned short* pa1 = t1 + (size_t)row1 * 512 + quad * 8;

  const f32x4 zz = {0.f, 0.f, 0.f, 0.f};
  f32x4 acc[2][16];
#pragma unroll
  for (int m = 0; m < 2; ++m)
#pragma unroll
    for (int n = 0; n < 16; ++n) acc[m][n] = zz;

  for (int ki = 0; ki < 8; ++ki) {
    __syncthreads();
    {
#pragma unroll
      for (int kk = 0; kk < 2; ++kk) {
        gl2lds16(pa0 + ki * 64 + kk * 32, &lA[(wv * 4 + kk) * 512]);
        gl2lds16(pa1 + ki * 64 + kk * 32, &lA[(wv * 4 + 2 + kk) * 512]);
#pragma unroll
        for (int i = 0; i < 4; ++i) {
          int n = wv * 4 + i;
          gl2lds16(wb2 + (size_t)(n * 16 + r16) * 512 + ki * 64 + kk * 32 + quad * 8,
                   &lB[(n * 2 + kk) * 512]);
        }
      }
    }
    __builtin_amdgcn_s_waitcnt(0);
    __syncthreads();
#pragma unroll
    for (int kk = 0; kk < 2; ++kk) {
      bf16_8 a0 = frag16(&lA[(wv * 4 + kk) * 512 + lane * 8]);
      bf16_8 a1 = frag16(&lA[(wv * 4 + 2 + kk) * 512 + lane * 8]);
#pragma unroll
      for (int n = 0; n < 16; ++n) {
        bf16_8 bf = frag16(&lB[(n * 2 + kk) * 512 + lane * 8]);
        acc[0][n] = __builtin_amdgcn_mfma_f32_16x16x32_bf16(a0, bf, acc[0][n], 0, 0, 0);
        acc[1][n] = __builtin_amdgcn_mfma_f32_16x16x32_bf16(a1, bf, acc[1][n], 0, 0, 0);
      }
    }
  }
  // ---- epilogue: per-wave padded scratch [16][264]; two m-passes; gemm3 ----
  __syncthreads();   // all compute LDS reads done before reuse
  unsigned short* reg = shm + wv * 4224;   // 16*264 = 4224 shorts = 8448 B/wave
  float bb3 = b3[r16];
#pragma unroll
  for (int m = 0; m < 2; ++m) {
#pragma unroll
    for (int n = 0; n < 16; ++n) {
      float bb = b2[n * 16 + r16];
#pragma unroll
      for (int rg = 0; rg < 4; ++rg)
        reg[(quad * 4 + rg) * 264 + n * 16 + r16] = f2b(gelu_exact(acc[m][n][rg] + bb));
    }
    // wave-private scratch: in-wave LDS ordering suffices (no barrier)
    f32x4 acc3 = zz;
#pragma unroll
    for (int ks = 0; ks < 8; ++ks) {
      bf16_8 a = frag16(&reg[r16 * 264 + ks * 32 + quad * 8]);
      bf16_8 b = frag16(wb3 + (size_t)r16 * 256 + ks * 32 + quad * 8);
      acc3 = __builtin_amdgcn_mfma_f32_16x16x32_bf16(a, b, acc3, 0, 0, 0);
    }
#pragma unroll
    for (int rg = 0; rg < 4; ++rg)
      dmo[(size_t)(e0 + wv * 32 + m * 16 + quad * 4 + rg) * DIN_ + r16] = acc3[rg] + bb3;
  }
}

// ---------------- fused edge MLP (fallback path) ----------------
__global__ __launch_bounds__(256, 3) void k_edge_mlp_mfma(
    const float* __restrict__ xout, const int* __restrict__ adj,
    const float* __restrict__ dmap,
    const float* __restrict__ lin_w, const float* __restrict__ lin_b,
    const unsigned short* __restrict__ wb1, const float* __restrict__ b1,
    const unsigned short* __restrict__ wb2, const float* __restrict__ b2,
    const unsigned short* __restrict__ wb3, const float* __restrict__ b3,
    float* __restrict__ dmo) {
  __shared__ unsigned short sLo[8448];
  __shared__ unsigned short sT1[32][520];
  unsigned short (*sA)[136]  = (unsigned short(*)[136])sLo;
  unsigned short (*sT2)[264] = (unsigned short(*)[264])sLo;

  const int tid  = threadIdx.x;
  const int e0   = blockIdx.x * 32;
  const int lane = tid & 63;
  const int wv   = tid >> 6;
  const int r16  = lane & 15;
  const int quad = lane >> 4;

  const int sr = tid >> 3;
  const int t8 = tid & 7;
  const int se = e0 + sr;
  const int vsrc = adj[se];
  const int vdst = adj[E_ + se];

  float4 pf0, pf1, pf2, pf3;
  float4 dm0, dm1, dm2, dm3;
  {
    const float4* sp = (const float4*)(xout + (size_t)vsrc * D_ + t8 * 16);
    pf0 = sp[0]; pf1 = sp[1]; pf2 = sp[2]; pf3 = sp[3];
  }

  const f32x4 zz = {0.f, 0.f, 0.f, 0.f};
  f32x4 acc1[8][2];
#pragma unroll
  for (int i = 0; i < 8; ++i) { acc1[i][0] = zz; acc1[i][1] = zz; }

  for (int c = 0; c < 6; ++c) {
    const int k0 = c * 128;
    __syncthreads();
    {
      unsigned short tmp[16];
      if (c == 2 || c == 3) {
        int jb = (c - 2) * 128 + t8 * 16;
#pragma unroll
        for (int j = 0; j < 16; ++j) {
          const float4* lw = (const float4*)(lin_w + (size_t)(jb + j) * DIN_);
          float4 w0 = lw[0], w1 = lw[1], w2 = lw[2], w3 = lw[3];
          float acc = lin_b[jb + j];
          acc += dm0.x * w0.x + dm0.y * w0.y + dm0.z * w0.z + dm0.w * w0.w;
          acc += dm1.x * w1.x + dm1.y * w1.y + dm1.z * w1.z + dm1.w * w1.w;
          acc += dm2.x * w2.x + dm2.y * w2.y + dm2.z * w2.z + dm2.w * w2.w;
          acc += dm3.x * w3.x + dm3.y * w3.y + dm3.z * w3.z + dm3.w * w3.w;
          tmp[j] = f2b(acc);
        }
      } else {
        tmp[0]  = f2b(pf0.x); tmp[1]  = f2b(pf0.y); tmp[2]  = f2b(pf0.z); tmp[3]  = f2b(pf0.w);
        tmp[4]  = f2b(pf1.x); tmp[5]  = f2b(pf1.y); tmp[6]  = f2b(pf1.z); tmp[7]  = f2b(pf1.w);
        tmp[8]  = f2b(pf2.x); tmp[9]  = f2b(pf2.y); tmp[10] = f2b(pf2.z); tmp[11] = f2b(pf2.w);
        tmp[12] = f2b(pf3.x); tmp[13] = f2b(pf3.y); tmp[14] = f2b(pf3.z); tmp[15] = f2b(pf3.w);
      }
      unsigned short* dstp = &sA[sr][t8 * 16];
      uint4 q0v = {pack2(tmp[0], tmp[1]),   pack2(tmp[2], tmp[3]),
                   pack2(tmp[4], tmp[5]),   pack2(tmp[6], tmp[7])};
      uint4 q1v = {pack2(tmp[8], tmp[9]),   pack2(tmp[10], tmp[11]),
                   pack2(tmp[12], tmp[13]), pack2(tmp[14], tmp[15])};
      *(uint4*)(dstp) = q0v;
      *(uint4*)(dstp + 8) = q1v;
    }
    if (c == 0) {
      const float4* sp = (const float4*)(xout + (size_t)vsrc * D_ + 128 + t8 * 16);
      pf0 = sp[0]; pf1 = sp[1]; pf2 = sp[2]; pf3 = sp[3];
    } else if (c == 1) {
      const float4* dp = (const float4*)(dmap + (size_t)se * DIN_);
      dm0 = ntload4(dp); dm1 = ntload4(dp + 1); dm2 = ntload4(dp + 2); dm3 = ntload4(dp + 3);
    } else if (c == 3) {
      const float4* sp = (const float4*)(xout + (size_t)vdst * D_ + t8 * 16);
      pf0 = sp[0]; pf1 = sp[1]; pf2 = sp[2]; pf3 = sp[3];
    } else if (c == 4) {
      const float4* sp = (const float4*)(xout + (size_t)vdst * D_ + 128 + t8 * 16);
      pf0 = sp[0]; pf1 = sp[1]; pf2 = sp[2]; pf3 = sp[3];
    }
    __syncthreads();
#pragma unroll
    for (int kk = 0; kk < 4; ++kk) {
      bf16_8 a0 = frag16(&sA[r16][kk * 32 + quad * 8]);
      bf16_8 a1 = frag16(&sA[16 + r16][kk * 32 + quad * 8]);
#pragma unroll
      for (int i = 0; i < 8; ++i) {
        const unsigned short* bp =
            wb1 + (size_t)(wv * 128 + i * 16 + r16) * 768 + k0 + kk * 32 + quad * 8;
        bf16_8 bf = frag16(bp);
        acc1[i][0] = __builtin_amdgcn_mfma_f32_16x16x32_bf16(a0, bf, acc1[i][0], 0, 0, 0);
        acc1[i][1] = __builtin_amdgcn_mfma_f32_16x16x32_bf16(a1, bf, acc1[i][1], 0, 0, 0);
      }
    }
  }
#pragma unroll
  for (int i = 0; i < 8; ++i) {
    int col = wv * 128 + i * 16 + r16;
    float bb = b1[col];
#pragma unroll
    for (int r = 0; r < 4; ++r) {
      int row = quad * 4 + r;
      sT1[row][col] = f2b(gelu_exact(acc1[i][0][r] + bb));
      sT1[row + 16][col] = f2b(gelu_exact(acc1[i][1][r] + bb));
    }
  }
  __syncthreads();

  f32x4 acc2[4][2];
#pragma unroll
  for (int i = 0; i < 4; ++i) { acc2[i][0] = zz; acc2[i][1] = zz; }
#pragma unroll 4
  for (int ks = 0; ks < 16; ++ks) {
    bf16_8 a0 = frag16(&sT1[r16][ks * 32 + quad * 8]);
    bf16_8 a1 = frag16(&sT1[16 + r16][ks * 32 + quad * 8]);
#pragma unroll
    for (int i = 0; i < 4; ++i) {
      const unsigned short* bp =
          wb2 + (size_t)(wv * 64 + i * 16 + r16) * 512 + ks * 32 + quad * 8;
      bf16_8 bf = frag16(bp);
      acc2[i][0] = __builtin_amdgcn_mfma_f32_16x16x32_bf16(a0, bf, acc2[i][0], 0, 0, 0);
      acc2[i][1] = __builtin_amdgcn_mfma_f32_16x16x32_bf16(a1, bf, acc2[i][1], 0, 0, 0);
    }
  }
#pragma unroll
  for (int i = 0; i < 4; ++i) {
    int col = wv * 64 + i * 16 + r16;
    float bb = b2[col];
#pragma unroll
    for (int m = 0; m < 2; ++m)
#pragma unroll
      for (int r = 0; r < 4; ++r) {
        int row = m * 16 + quad * 4 + r;
        sT2[row][col] = f2b(gelu_exact(acc2[i][m][r] + bb));
      }
  }
  __syncthreads();

  if (wv < 2) {
    f32x4 acc3 = zz;
#pragma unroll
    for (int ks = 0; ks < 8; ++ks) {
      bf16_8 a = frag16(&sT2[wv * 16 + r16][ks * 32 + quad * 8]);
      bf16_8 b = frag16(wb3 + (size_t)r16 * 256 + ks * 32 + quad * 8);
      acc3 = __builtin_amdgcn_mfma_f32_16x16x32_bf16(a, b, acc3, 0, 0, 0);
    }
    float bb = b3[r16];
#pragma unroll
    for (int r = 0; r < 4; ++r) {
      int row = wv * 16 + quad * 4 + r;
      __builtin_nontemporal_store(acc3[r] + bb, &dmo[(size_t)(e0 + row) * DIN_ + r16]);
    }
  }
}

extern "C" void kernel_launch(void* const* d_in, const int* in_sizes, int n_in,
                              void* d_out, int out_size, void* d_ws, size_t ws_size,
                              hipStream_t stream) {
  const float* input = (const float*)d_in[0];
  const int*   adj   = (const int*)d_in[1];
  const float* h0    = (const float*)d_in[2];
  const void*  lamda = d_in[3];
  const float* alpha = (const float*)d_in[4];
  const void*  lll   = d_in[5];
  const float* dmap  = (const float*)d_in[6];
  const float* nrm   = (const float*)d_in[7];
  const float* Wl    = (const float*)d_in[8];
  const float* Wg    = (const float*)d_in[9];
  const float* lin_w = (const float*)d_in[10];
  const float* lin_b = (const float*)d_in[11];
  const float* w1    = (const float*)d_in[12];
  const float* b1    = (const float*)d_in[13];
  const float* w2    = (const float*)d_in[14];
  const float* b2    = (const float*)d_in[15];
  const float* w3    = (const float*)d_in[16];
  const float* b3    = (const float*)d_in[17];
  const float* ipw   = (const float*)d_in[18];
  const float* ipb   = (const float*)d_in[19];
  const float* opw   = (const float*)d_in[20];
  const float* opb   = (const float*)d_in[21];
  float* out = (float*)d_out;
  float* dmo = out + (size_t)N_ * D_;

  // ---- workspace layout ----
  float* ws   = (float*)d_ws;
  float* xout = ws;                               // N*D f32
  float* qkv  = xout + (size_t)N_ * D_;           // N*3D f32
  float* atto = qkv  + (size_t)N_ * 3 * D_;       // N*D f32
  float* hgl  = atto + (size_t)N_ * D_;           // N*D f32
  unsigned short* wb1 = (unsigned short*)(hgl + (size_t)N_ * D_);  // 512*768
  unsigned short* wb2 = wb1 + 512 * 768;          // 256*512
  unsigned short* wb3 = wb2 + 256 * 512;          // 16*256
  unsigned short* Qb  = wb3 + 16 * 256;           // 2*N*128
  unsigned short* Kb  = Qb + 2 * N_ * HD_;        // 2*N*128
  unsigned short* Vt  = Kb + 2 * N_ * HD_;        // 2*128*N
  unsigned short* t1b = Vt + 2 * HD_ * N_;        // E*512  (fast path only)
  unsigned short* t2b = t1b + (size_t)E_ * 512;   // E*256  (eab; t2 no longer materialized)
  unsigned short* eab = t2b;                      // E*256
  int* cnt  = (int*)(t2b + (size_t)E_ * 256);     // 4096
  int* off  = cnt + 4096;                         // 4097
  int* cur  = off + 4100;                         // 4096
  int* perm = cur + 4096;                         // E
  unsigned short* xbp = (unsigned short*)(perm + E_);  // N*D bf16
  unsigned short* lwb = xbp + (size_t)N_ * D_;    // 256*16 bf16 lin_w
  unsigned short* inb = lwb + 256 * DIN_;         // N*D bf16 input
  unsigned short* h0b = inb + (size_t)N_ * D_;    // N*D bf16 h0
  unsigned short* hgb = h0b + (size_t)N_ * D_;    // N*D bf16 h_global
  unsigned short* wqb = hgb + (size_t)N_ * D_;    // 768*256 bf16 in_proj
  unsigned short* wlT = wqb + 768 * 256;          // 256*512 bf16 Wl^T
  unsigned short* wgT = wlT + 256 * 512;          // 256*512 bf16 Wg^T
  unsigned short* opwb = wgT + 256 * 512;         // 256*256 bf16 out_proj
  unsigned short* attob = (unsigned short*)qkv;   // N*D bf16 (qkv region reused post-split)
  const size_t fast_need = (size_t)((char*)(opwb + 256 * 256) - (char*)d_ws);
  const bool fast = ws_size >= fast_need;

  if (fast) {
    // merged preps: weights, Wl/Wg transpose, input/h0 bf16
    k_prep_w<<<dim3((794624 + 255) / 256), 256, 0, stream>>>(
        w1, w2, w3, lin_w, ipw, opw, wb1, wb2, wb3, lwb, wqb, opwb);
    k_prep_t<<<dim3((262144 + 255) / 256), 256, 0, stream>>>(Wl, Wg, wlT, wgT);
    k_prep_x<<<dim3((2097152 + 255) / 256), 256, 0, stream>>>(input, h0, inb, h0b);

    // edge_attr via MFMA, CSR build, gather aggregation
    k_edge_attr_mfma<<<dim3(E_ / 64), 256, 0, stream>>>(dmap, lwb, lin_b, eab);
    k_zero<<<dim3(16), 256, 0, stream>>>(cnt, 4096);
    k_hist<<<dim3(E_ / 256), 256, 0, stream>>>(adj, cnt);
    k_scan<<<dim3(1), 1024, 0, stream>>>(cnt, off, cur);
    k_bucket<<<dim3(E_ / 256), 256, 0, stream>>>(adj, cur, perm);
    k_gather<<<dim3(N_), 256, 0, stream>>>(input, adj, eab, nrm, off, perm, xout);
    k_f2b<<<dim3(N_ * D_ / 256), 256, 0, stream>>>(xout, xbp, N_ * D_);

    // MHA: MFMA qkv -> split -> MFMA flash attn (dual out) -> MFMA out_proj
    k_qkv_mfma<<<dim3(192), 256, 0, stream>>>(inb, wqb, ipb, qkv);
    k_qk2b<<<dim3(N_ * 512 / 8 / 256), 256, 0, stream>>>(qkv, Qb, Kb);
    k_v2t<<<dim3(N_ / 64, 2), 256, 0, stream>>>(qkv, Vt);
    k_attn_mfma<<<dim3(N_ / 16, 2), 256, 0, stream>>>(Qb, Kb, Vt, atto, attob);
    k_outproj_mfma<<<dim3(64), 256, 0, stream>>>(attob, opwb, opb, hgl, hgb);

    // output[N,D] via MFMA
    k_final_mfma<<<dim3(64), 256, 0, stream>>>(xbp, h0b, hgb, wlT, wgT,
                                               xout, hgl, h0, alpha, lamda, lll, out);

    // dm_out[E,16]: gemm1 -> fused gemm2+3 (t2 never hits HBM)
    k_mlp_gemm1<<<dim3(4096), 256, 0, stream>>>(xbp, adj, eab, wb1, b1, t1b);
    k_mlp_gemm23<<<dim3(E_ / 128), 256, 0, stream>>>(t1b, wb2, b2, wb3, b3, dmo);
  } else {
    k_f2b<<<dim3((512 * 768 + 255) / 256), 256, 0, stream>>>(w1, wb1, 512 * 768);
    k_f2b<<<dim3((256 * 512 + 255) / 256), 256, 0, stream>>>(w2, wb2, 256 * 512);
    k_f2b<<<dim3((16 * 256 + 255) / 256), 256, 0, stream>>>(w3, wb3, 16 * 256);
    k_copy4<<<dim3(N_ * D_ / 4 / 256), 256, 0, stream>>>((const float4*)input, (float4*)xout,
                                                         N_ * D_ / 4);
    k_scatter<<<dim3(E_ / 4), 256, 0, stream>>>(input, adj, dmap, nrm, lin_w, lin_b, xout);
    k_gemm_bt<<<dim3(D3_ / 64, N_ / 64), 256, 0, stream>>>(input, ipw, ipb, qkv, N_, D3_, D_);
    k_qk2b<<<dim3(N_ * 512 / 8 / 256), 256, 0, stream>>>(qkv, Qb, Kb);
    k_v2t<<<dim3(N_ / 64, 2), 256, 0, stream>>>(qkv, Vt);
    k_attn_mfma<<<dim3(N_ / 16, 2), 256, 0, stream>>>(Qb, Kb, Vt, atto, (unsigned short*)qkv);
    k_gemm_bt<<<dim3(D_ / 64, N_ / 64), 256, 0, stream>>>(atto, opw, opb, hgl, N_, D_, D_);
    k_final<<<dim3(4, N_ / 64), 256, 0, stream>>>(xout, hgl, h0, Wl, Wg, alpha, lamda, lll, out);
    k_edge_mlp_mfma<<<dim3(E_ / 32), 256, 0, stream>>>(xout, adj, dmap, lin_w, lin_b,
                                                       wb1, b1, wb2, b2, wb3, b3, dmo);
  }
}